// Round 8
// baseline (528.772 us; speedup 1.0000x reference)
//
#include <hip/hip_runtime.h>
#include <math.h>

#define N_NODES 50000
#define N_EDGES 600000
#define D 128
#define N_GRAPHS 512
#define N_CLASSES 10
#define N_LAYERS 4
#define NBLK_SCAN 196   // ceil(50000/256)

typedef __attribute__((ext_vector_type(8))) short bf16x8;
typedef __attribute__((ext_vector_type(4))) float f32x4;

__device__ inline unsigned short f2bf(float f) {
    union { float f; unsigned int u; } v; v.f = f;
    unsigned int r = (v.u + 0x7fffu + ((v.u >> 16) & 1u)) >> 16;
    return (unsigned short)r;
}
__device__ inline float bf2f(unsigned short u) {
    union { unsigned int u; float f; } v; v.u = ((unsigned int)u) << 16;
    return v.f;
}

// ---------------- zero fill ----------------
__global__ __launch_bounds__(256) void fill_zero4(float4* p, int n4) {
    int i = blockIdx.x * 256 + threadIdx.x;
    if (i < n4) p[i] = make_float4(0.f, 0.f, 0.f, 0.f);
}

// ---------------- fused init: h bf16 into catA[:,128:] + weight bf16 + combined bias ----------------
// bc layout [L][512]: j<128: bih_r+bhh_r ; 128..256: bih_z+bhh_z ; 256..384: bih_n ; 384..512: bhh_n
__global__ __launch_bounds__(256) void init_all(const float* __restrict__ h_in,
                                                const float* __restrict__ Ws,
                                                const float* __restrict__ Wih,
                                                const float* __restrict__ Whh,
                                                const float* __restrict__ bih,
                                                const float* __restrict__ bhh,
                                                unsigned short* __restrict__ catA,
                                                unsigned short* __restrict__ Ws_bf,
                                                unsigned short* __restrict__ Wih_bf,
                                                unsigned short* __restrict__ Whh_bf,
                                                float* __restrict__ bc) {
    int idx = blockIdx.x * 256 + threadIdx.x;
    if (idx < N_NODES * D) {
        int i = idx >> 7;
        int c = idx & 127;
        catA[(size_t)i * 256 + 128 + c] = f2bf(h_in[idx]);
    }
    if (idx < N_LAYERS * D * D) Ws_bf[idx] = f2bf(Ws[idx]);
    if (idx < N_LAYERS * 3 * D * D) {
        Wih_bf[idx] = f2bf(Wih[idx]);
        Whh_bf[idx] = f2bf(Whh[idx]);
    }
    if (idx < N_LAYERS * 512) {
        int l = idx >> 9;
        int j = idx & 511;
        const float* bi = bih + (size_t)l * 384;
        const float* bh = bhh + (size_t)l * 384;
        float v;
        if (j < 256) v = bi[j] + bh[j];
        else if (j < 384) v = bi[j];
        else v = bh[j - 128];
        bc[idx] = v;
    }
}

// ---------------- build B_cat2[l][512][256], gate-interleaved columns ----------------
// j' = ch*4 + gate (gate: 0=r, 1=z, 2=i_n, 3=h_n); maps to old j = gate*128 + ch.
__global__ __launch_bounds__(256) void build_bcat(const unsigned short* __restrict__ Wp,
                                                  const unsigned short* __restrict__ Whh,
                                                  unsigned short* __restrict__ Bcat) {
    int idx = blockIdx.x * 256 + threadIdx.x;   // L*512*256
    if (idx >= N_LAYERS * 512 * 256) return;
    int l = idx >> 17;
    int rem = idx & 131071;
    int jp = rem >> 8;
    int k = rem & 255;
    int gate = jp & 3;
    int ch = jp >> 2;
    int j = gate * 128 + ch;
    unsigned short v = 0;
    if (j < 256) {
        v = (k < 128) ? Wp[((size_t)l * 384 + j) * 128 + k]
                      : Whh[((size_t)l * 384 + j) * 128 + (k - 128)];
    } else if (j < 384) {
        v = (k < 128) ? Wp[((size_t)l * 384 + j) * 128 + k] : (unsigned short)0;
    } else {
        v = (k >= 128) ? Whh[((size_t)l * 384 + (j - 128)) * 128 + (k - 128)] : (unsigned short)0;
    }
    Bcat[idx] = v;
}

// ---------------- CSR build ----------------
__global__ __launch_bounds__(256) void hist_dst(const int* __restrict__ dst,
                                                int* __restrict__ deg) {
    int e = blockIdx.x * 256 + threadIdx.x;
    if (e < N_EDGES) atomicAdd(&deg[dst[e]], 1);
}

__global__ __launch_bounds__(256) void block_sum(const int* __restrict__ deg,
                                                 int* __restrict__ bsum) {
    __shared__ int s[256];
    int t = threadIdx.x;
    int i = blockIdx.x * 256 + t;
    s[t] = (i < N_NODES) ? deg[i] : 0;
    __syncthreads();
    for (int o = 128; o > 0; o >>= 1) {
        if (t < o) s[t] += s[t + o];
        __syncthreads();
    }
    if (t == 0) bsum[blockIdx.x] = s[0];
}

__global__ __launch_bounds__(256) void scan_partials(const int* __restrict__ bsum,
                                                     int* __restrict__ boff,
                                                     int* __restrict__ row_ptr) {
    __shared__ int s[256];
    int t = threadIdx.x;
    int v = (t < NBLK_SCAN) ? bsum[t] : 0;
    s[t] = v;
    __syncthreads();
    for (int o = 1; o < 256; o <<= 1) {
        int x = (t >= o) ? s[t - o] : 0;
        __syncthreads();
        s[t] += x;
        __syncthreads();
    }
    if (t < NBLK_SCAN) boff[t] = s[t] - v;   // exclusive
    if (t == 255) row_ptr[N_NODES] = s[255];
}

__global__ __launch_bounds__(256) void scan_final(const int* __restrict__ deg,
                                                  const int* __restrict__ boff,
                                                  int* __restrict__ row_ptr,
                                                  int* __restrict__ pos) {
    __shared__ int s[256];
    int t = threadIdx.x;
    int i = blockIdx.x * 256 + t;
    int v = (i < N_NODES) ? deg[i] : 0;
    s[t] = v;
    __syncthreads();
    for (int o = 1; o < 256; o <<= 1) {
        int x = (t >= o) ? s[t - o] : 0;
        __syncthreads();
        s[t] += x;
        __syncthreads();
    }
    int excl = s[t] - v + boff[blockIdx.x];
    if (i < N_NODES) {
        row_ptr[i] = excl;
        pos[i] = excl;
    }
}

__global__ __launch_bounds__(256) void fill_csr(const int* __restrict__ src,
                                                const int* __restrict__ dst,
                                                int* __restrict__ pos,
                                                int* __restrict__ csr_src) {
    int e = blockIdx.x * 256 + threadIdx.x;
    if (e >= N_EDGES) return;
    int p = atomicAdd(&pos[dst[e]], 1);
    csr_src[p] = src[e];
}

// ---------------- gather: cat[n, 0:128] = sum_{e:dst=n} cat[src[e], 128:256] ----------------
// Reads only cols 128:256, writes only cols 0:128 -> no intra-dispatch hazard.
__global__ __launch_bounds__(256) void gather_agg(unsigned short* __restrict__ cat,
                                                  const int* __restrict__ row_ptr,
                                                  const int* __restrict__ csr_src) {
    int t = threadIdx.x;
    int node = blockIdx.x * 16 + (t >> 4);
    int c8 = (t & 15) * 8;
    if (node >= N_NODES) return;
    int b = row_ptr[node];
    int e2 = row_ptr[node + 1];
    float acc0[8] = {}, acc1[8] = {}, acc2[8] = {}, acc3[8] = {};
    int e = b;
    for (; e + 4 <= e2; e += 4) {
        int s0 = csr_src[e];
        int s1 = csr_src[e + 1];
        int s2 = csr_src[e + 2];
        int s3 = csr_src[e + 3];
        bf16x8 v0 = *(const bf16x8*)(cat + (size_t)s0 * 256 + 128 + c8);
        bf16x8 v1 = *(const bf16x8*)(cat + (size_t)s1 * 256 + 128 + c8);
        bf16x8 v2 = *(const bf16x8*)(cat + (size_t)s2 * 256 + 128 + c8);
        bf16x8 v3 = *(const bf16x8*)(cat + (size_t)s3 * 256 + 128 + c8);
        #pragma unroll
        for (int j = 0; j < 8; ++j) {
            acc0[j] += bf2f((unsigned short)v0[j]);
            acc1[j] += bf2f((unsigned short)v1[j]);
            acc2[j] += bf2f((unsigned short)v2[j]);
            acc3[j] += bf2f((unsigned short)v3[j]);
        }
    }
    for (; e < e2; ++e) {
        int s0 = csr_src[e];
        bf16x8 v0 = *(const bf16x8*)(cat + (size_t)s0 * 256 + 128 + c8);
        #pragma unroll
        for (int j = 0; j < 8; ++j) acc0[j] += bf2f((unsigned short)v0[j]);
    }
    bf16x8 ov;
    #pragma unroll
    for (int j = 0; j < 8; ++j) ov[j] = (short)f2bf((acc0[j] + acc1[j]) + (acc2[j] + acc3[j]));
    *(bf16x8*)(cat + (size_t)node * 256 + c8) = ov;
}

// ---------------- generic bf16 MFMA GEMM (used for the tiny W' precompute) ----------------
__global__ __launch_bounds__(256) void gemm_bf16(const unsigned short* __restrict__ A, int Ap,
                                                 const unsigned short* __restrict__ W, int Wp,
                                                 unsigned short* __restrict__ out, int Op,
                                                 int M, int Kd,
                                                 size_t lsA, size_t lsW, size_t lsO) {
    A += (size_t)blockIdx.z * lsA;
    W += (size_t)blockIdx.z * lsW;
    out += (size_t)blockIdx.z * lsO;

    __shared__ unsigned short As[128 * 72];
    __shared__ unsigned short Bs[128 * 72];

    const int tid = threadIdx.x;
    const int i0 = blockIdx.x * 128;
    const int j0 = blockIdx.y * 128;

    const int wave = tid >> 6;
    const int lane = tid & 63;
    const int m16 = lane & 15;
    const int quad = lane >> 4;
    const int mr = (wave & 1) * 64;
    const int nc = (wave >> 1) * 64;

    f32x4 acc[4][4];
    #pragma unroll
    for (int a = 0; a < 4; ++a)
        #pragma unroll
        for (int b = 0; b < 4; ++b)
            acc[a][b] = (f32x4){0.f, 0.f, 0.f, 0.f};

    const int r0 = tid >> 3;
    const int kk = (tid & 7) * 8;

    for (int kc = 0; kc < Kd; kc += 64) {
        if (kc) __syncthreads();
        #pragma unroll
        for (int it = 0; it < 4; ++it) {
            int r = r0 + it * 32;
            int gi_ = i0 + r;
            bf16x8 av = {0, 0, 0, 0, 0, 0, 0, 0};
            if (gi_ < M) av = *(const bf16x8*)(A + (size_t)gi_ * Ap + kc + kk);
            *(bf16x8*)&As[r * 72 + kk] = av;
            *(bf16x8*)&Bs[r * 72 + kk] = *(const bf16x8*)(W + (size_t)(j0 + r) * Wp + kc + kk);
        }
        __syncthreads();

        #pragma unroll
        for (int ks = 0; ks < 64; ks += 32) {
            bf16x8 af[4], bf_[4];
            #pragma unroll
            for (int rt = 0; rt < 4; ++rt)
                af[rt] = *(const bf16x8*)&As[(mr + rt * 16 + m16) * 72 + ks + quad * 8];
            #pragma unroll
            for (int ct = 0; ct < 4; ++ct)
                bf_[ct] = *(const bf16x8*)&Bs[(nc + ct * 16 + m16) * 72 + ks + quad * 8];
            #pragma unroll
            for (int rt = 0; rt < 4; ++rt)
                #pragma unroll
                for (int ct = 0; ct < 4; ++ct)
                    acc[rt][ct] = __builtin_amdgcn_mfma_f32_16x16x32_bf16(
                        af[rt], bf_[ct], acc[rt][ct], 0, 0, 0);
        }
    }

    #pragma unroll
    for (int rt = 0; rt < 4; ++rt) {
        #pragma unroll
        for (int r4 = 0; r4 < 4; ++r4) {
            int i = i0 + mr + rt * 16 + quad * 4 + r4;
            if (i >= M) continue;
            #pragma unroll
            for (int ct = 0; ct < 4; ++ct) {
                int j = j0 + nc + ct * 16 + m16;
                out[(size_t)i * Op + j] = f2bf(acc[rt][ct][r4]);
            }
        }
    }
}

// ---------------- fused GEMM + GRU gates, operand-swapped ----------------
// As = weights (Bcat2 layer [512][256], gate-interleaved j'), Bs = cat node rows.
// D[row=j'][col=node]: lane reg r4 = gate (j'%4), so each lane's f32x4 acc holds
// (r,z,i_n,h_n) for one (node, channel) directly -> no transpose, no extra barriers.
// Reads catR, writes catW (ping-pong: no inter-block read/write race).
__global__ __launch_bounds__(256) void gemm_gru(const unsigned short* __restrict__ catR,
                                                unsigned short* __restrict__ catW,
                                                const unsigned short* __restrict__ W,
                                                const float* __restrict__ bc) {
    __shared__ unsigned short As[128 * 72];   // weight rows (j')
    __shared__ unsigned short Bs[128 * 72];   // node rows

    const int tid = threadIdx.x;
    const int i0 = blockIdx.x * 128;   // node base
    const int j0 = blockIdx.y * 128;   // j' base

    const int wave = tid >> 6;
    const int lane = tid & 63;
    const int m16 = lane & 15;
    const int quad = lane >> 4;
    const int mr = (wave & 1) * 64;    // j' sub-tile
    const int nc = (wave >> 1) * 64;   // node sub-tile

    f32x4 acc[4][4];
    #pragma unroll
    for (int a = 0; a < 4; ++a)
        #pragma unroll
        for (int b = 0; b < 4; ++b)
            acc[a][b] = (f32x4){0.f, 0.f, 0.f, 0.f};

    const int r0 = tid >> 3;
    const int kk = (tid & 7) * 8;

    for (int kc = 0; kc < 256; kc += 64) {
        if (kc) __syncthreads();
        #pragma unroll
        for (int it = 0; it < 4; ++it) {
            int r = r0 + it * 32;
            *(bf16x8*)&As[r * 72 + kk] = *(const bf16x8*)(W + (size_t)(j0 + r) * 256 + kc + kk);
            int gn = i0 + r;
            bf16x8 bv = {0, 0, 0, 0, 0, 0, 0, 0};
            if (gn < N_NODES) bv = *(const bf16x8*)(catR + (size_t)gn * 256 + kc + kk);
            *(bf16x8*)&Bs[r * 72 + kk] = bv;
        }
        __syncthreads();

        #pragma unroll
        for (int ks = 0; ks < 64; ks += 32) {
            bf16x8 af[4], bf_[4];
            #pragma unroll
            for (int rt = 0; rt < 4; ++rt)
                af[rt] = *(const bf16x8*)&As[(mr + rt * 16 + m16) * 72 + ks + quad * 8];
            #pragma unroll
            for (int ct = 0; ct < 4; ++ct)
                bf_[ct] = *(const bf16x8*)&Bs[(nc + ct * 16 + m16) * 72 + ks + quad * 8];
            #pragma unroll
            for (int rt = 0; rt < 4; ++rt)
                #pragma unroll
                for (int ct = 0; ct < 4; ++ct)
                    acc[rt][ct] = __builtin_amdgcn_mfma_f32_16x16x32_bf16(
                        af[rt], bf_[ct], acc[rt][ct], 0, 0, 0);
        }
    }

    // epilogue: gate nonlinearity straight from accumulators
    const int chw = blockIdx.y * 32 + (wave & 1) * 16;   // channel base for this wave
    #pragma unroll
    for (int rt = 0; rt < 4; ++rt) {
        int ch = chw + rt * 4 + quad;
        float br  = bc[ch];
        float bz  = bc[128 + ch];
        float bni = bc[256 + ch];
        float bnh = bc[384 + ch];
        #pragma unroll
        for (int ct = 0; ct < 4; ++ct) {
            int node = i0 + nc + ct * 16 + m16;
            if (node >= N_NODES) continue;
            float h_old = bf2f(catR[(size_t)node * 256 + 128 + ch]);
            float r = 1.f / (1.f + __expf(-(acc[rt][ct][0] + br)));
            float z = 1.f / (1.f + __expf(-(acc[rt][ct][1] + bz)));
            float a = acc[rt][ct][2] + bni + r * (acc[rt][ct][3] + bnh);
            a = fminf(fmaxf(a, -20.f), 20.f);
            float t2 = __expf(2.f * a);
            float n = (t2 - 1.f) / (t2 + 1.f);
            float o = (1.f - z) * n + z * h_old;
            o = o > 0.f ? o : 0.f;
            catW[(size_t)node * 256 + 128 + ch] = f2bf(o);
        }
    }
}

// ---------------- mean pool over sorted batch (bf16 h in cat) ----------------
__global__ __launch_bounds__(128) void pool_sorted(const unsigned short* __restrict__ cat,
                                                   const int* __restrict__ batch,
                                                   float* __restrict__ hg) {
    int g = blockIdx.x;
    int c = threadIdx.x;
    int lo = 0, hi = N_NODES;
    while (lo < hi) { int mid = (lo + hi) >> 1; if (batch[mid] < g) lo = mid + 1; else hi = mid; }
    int start = lo;
    lo = start; hi = N_NODES;
    while (lo < hi) { int mid = (lo + hi) >> 1; if (batch[mid] < g + 1) lo = mid + 1; else hi = mid; }
    int end = lo;
    float s = 0.f;
    for (int i = start; i < end; ++i) s += bf2f(cat[(size_t)i * 256 + 128 + c]);
    float cnt = (float)(end - start);
    hg[(size_t)g * D + c] = s / fmaxf(cnt, 1.f);
}

// ---------------- fc1 + elu ----------------
__global__ __launch_bounds__(128) void fc1_elu(const float* __restrict__ hg,
                                               const float* __restrict__ w,
                                               const float* __restrict__ b,
                                               float* __restrict__ z) {
    __shared__ float row[128];
    int g = blockIdx.x;
    int j = threadIdx.x;
    row[j] = hg[(size_t)g * 128 + j];
    __syncthreads();
    float acc = b[j];
    const float* wr = w + (size_t)j * 128;
    #pragma unroll 4
    for (int k = 0; k < 128; ++k) acc += row[k] * wr[k];
    z[(size_t)g * 128 + j] = acc > 0.f ? acc : (expf(acc) - 1.f);
}

// ---------------- fc2 ----------------
__global__ __launch_bounds__(64) void fc2_k(const float* __restrict__ z,
                                            const float* __restrict__ w,
                                            const float* __restrict__ b,
                                            float* __restrict__ logits) {
    __shared__ float row[128];
    int g = blockIdx.x;
    int t = threadIdx.x;
    row[t] = z[(size_t)g * 128 + t];
    row[t + 64] = z[(size_t)g * 128 + 64 + t];
    __syncthreads();
    if (t < N_CLASSES) {
        float acc = b[t];
        const float* wr = w + (size_t)t * 128;
        #pragma unroll 4
        for (int k = 0; k < 128; ++k) acc += row[k] * wr[k];
        logits[(size_t)g * N_CLASSES + t] = acc;
    }
}

// ---------------- log_softmax over axis 0 ----------------
__global__ __launch_bounds__(512) void logsoftmax_axis0(const float* __restrict__ logits,
                                                        float* __restrict__ out) {
    __shared__ float red[512];
    int c = blockIdx.x;
    int g = threadIdx.x;
    float x = logits[(size_t)g * N_CLASSES + c];
    red[g] = x;
    __syncthreads();
    for (int s = 256; s > 0; s >>= 1) {
        if (g < s) red[g] = fmaxf(red[g], red[g + s]);
        __syncthreads();
    }
    float mx = red[0];
    __syncthreads();
    red[g] = expf(x - mx);
    __syncthreads();
    for (int s = 256; s > 0; s >>= 1) {
        if (g < s) red[g] += red[g + s];
        __syncthreads();
    }
    float lse = mx + logf(red[0]);
    out[(size_t)g * N_CLASSES + c] = x - lse;
}

// ---------------- launch ----------------
extern "C" void kernel_launch(void* const* d_in, const int* in_sizes, int n_in,
                              void* d_out, int out_size, void* d_ws, size_t ws_size,
                              hipStream_t stream) {
    const float* h_in   = (const float*)d_in[0];
    const int*   eidx   = (const int*)d_in[1];
    const int*   batch  = (const int*)d_in[3];
    const float* Ws     = (const float*)d_in[4];
    const float* W_ih   = (const float*)d_in[5];
    const float* W_hh   = (const float*)d_in[6];
    const float* b_ih   = (const float*)d_in[7];
    const float* b_hh   = (const float*)d_in[8];
    const float* fc1_w  = (const float*)d_in[9];
    const float* fc1_b  = (const float*)d_in[10];
    const float* fc2_w  = (const float*)d_in[11];
    const float* fc2_b  = (const float*)d_in[12];
    float* out = (float*)d_out;

    char* ws = (char*)d_ws;
    size_t off = 0;
    auto alloc = [&](size_t bytes) {
        void* p = ws + off;
        off += (bytes + 255) & ~(size_t)255;
        return p;
    };
    unsigned short* catA = (unsigned short*)alloc((size_t)N_NODES * 256 * 2);  // [agg | h] bf16
    unsigned short* catB = (unsigned short*)alloc((size_t)N_NODES * 256 * 2);
    unsigned short* Ws_bf  = (unsigned short*)alloc((size_t)N_LAYERS * D * D * 2);
    unsigned short* Wih_bf = (unsigned short*)alloc((size_t)N_LAYERS * 3 * D * D * 2);
    unsigned short* Whh_bf = (unsigned short*)alloc((size_t)N_LAYERS * 3 * D * D * 2);
    unsigned short* Wp_bf  = (unsigned short*)alloc((size_t)N_LAYERS * 3 * D * D * 2);  // Wih @ Ws^T
    unsigned short* Bcat   = (unsigned short*)alloc((size_t)N_LAYERS * 512 * 256 * 2);
    float* bc   = (float*)alloc((size_t)N_LAYERS * 512 * 4);
    float* hg   = (float*)alloc((size_t)N_GRAPHS * D * 4);
    float* zb   = (float*)alloc((size_t)N_GRAPHS * D * 4);
    float* lgts = (float*)alloc((size_t)N_GRAPHS * N_CLASSES * 4);
    int* deg     = (int*)alloc((size_t)N_NODES * 4);
    int* row_ptr = (int*)alloc((size_t)(N_NODES + 1) * 4);
    int* pos     = (int*)alloc((size_t)N_NODES * 4);
    int* csr_src = (int*)alloc((size_t)N_EDGES * 4);
    int* bsum    = (int*)alloc((size_t)NBLK_SCAN * 4);
    int* boff    = (int*)alloc((size_t)NBLK_SCAN * 4);

    const int* src = eidx;
    const int* dst = eidx + N_EDGES;

    init_all<<<(N_NODES * D + 255) / 256, 256, 0, stream>>>(
        h_in, Ws, W_ih, W_hh, b_ih, b_hh, catA, Ws_bf, Wih_bf, Whh_bf, bc);

    // W'_l = Wih_l @ Ws_l^T, batched over layers via grid.z
    gemm_bf16<<<dim3(3, 1, N_LAYERS), 256, 0, stream>>>(
        Wih_bf, 128, Ws_bf, 128, Wp_bf, 128, 384, 128,
        (size_t)384 * 128, (size_t)128 * 128, (size_t)384 * 128);
    build_bcat<<<(N_LAYERS * 512 * 256 + 255) / 256, 256, 0, stream>>>(Wp_bf, Whh_bf, Bcat);

    // CSR build (edges static) — distributed scan
    fill_zero4<<<(N_NODES / 4 + 255) / 256, 256, 0, stream>>>((float4*)deg, N_NODES / 4);
    hist_dst<<<(N_EDGES + 255) / 256, 256, 0, stream>>>(dst, deg);
    block_sum<<<NBLK_SCAN, 256, 0, stream>>>(deg, bsum);
    scan_partials<<<1, 256, 0, stream>>>(bsum, boff, row_ptr);
    scan_final<<<NBLK_SCAN, 256, 0, stream>>>(deg, boff, row_ptr, pos);
    fill_csr<<<(N_EDGES + 255) / 256, 256, 0, stream>>>(src, dst, pos, csr_src);

    const int mtiles = (N_NODES + 127) / 128;   // 391
    for (int l = 0; l < N_LAYERS; ++l) {
        unsigned short* catR = (l & 1) ? catB : catA;
        unsigned short* catW = (l & 1) ? catA : catB;
        // catR[:,0:128] = gather of catR[:,128:256]  (agg of h)
        gather_agg<<<(N_NODES + 15) / 16, 256, 0, stream>>>(catR, row_ptr, csr_src);
        // fused: gates(catR @ Bcat2_l^T) -> catW[:,128:256] (new h, bf16)
        gemm_gru<<<dim3(mtiles, 4), 256, 0, stream>>>(
            catR, catW, Bcat + (size_t)l * 512 * 256, bc + (size_t)l * 512);
    }

    // after 4 layers (even), final h lives in catA[:,128:256]
    pool_sorted<<<N_GRAPHS, 128, 0, stream>>>(catA, batch, hg);
    fc1_elu<<<N_GRAPHS, 128, 0, stream>>>(hg, fc1_w, fc1_b, zb);
    fc2_k<<<N_GRAPHS, 64, 0, stream>>>(zb, fc2_w, fc2_b, lgts);
    logsoftmax_axis0<<<N_CLASSES, 512, 0, stream>>>(lgts, out);
}

// Round 9
// 514.871 us; speedup vs baseline: 1.0270x; 1.0270x over previous
//
#include <hip/hip_runtime.h>
#include <math.h>

#define N_NODES 50000
#define N_EDGES 600000
#define D 128
#define N_GRAPHS 512
#define N_CLASSES 10
#define N_LAYERS 4
#define NBLK_SCAN 196   // ceil(50000/256)

typedef __attribute__((ext_vector_type(8))) short bf16x8;
typedef __attribute__((ext_vector_type(4))) float f32x4;

__device__ inline unsigned short f2bf(float f) {
    union { float f; unsigned int u; } v; v.f = f;
    unsigned int r = (v.u + 0x7fffu + ((v.u >> 16) & 1u)) >> 16;
    return (unsigned short)r;
}
__device__ inline float bf2f(unsigned short u) {
    union { unsigned int u; float f; } v; v.u = ((unsigned int)u) << 16;
    return v.f;
}

// ---------------- zero fill ----------------
__global__ __launch_bounds__(256) void fill_zero4(float4* p, int n4) {
    int i = blockIdx.x * 256 + threadIdx.x;
    if (i < n4) p[i] = make_float4(0.f, 0.f, 0.f, 0.f);
}

// ---------------- fused init: h bf16 into catA[:,128:] + weight bf16 + combined bias ----------------
// bc layout [L][512]: j<128: bih_r+bhh_r ; 128..256: bih_z+bhh_z ; 256..384: bih_n ; 384..512: bhh_n
__global__ __launch_bounds__(256) void init_all(const float* __restrict__ h_in,
                                                const float* __restrict__ Ws,
                                                const float* __restrict__ Wih,
                                                const float* __restrict__ Whh,
                                                const float* __restrict__ bih,
                                                const float* __restrict__ bhh,
                                                unsigned short* __restrict__ catA,
                                                unsigned short* __restrict__ Ws_bf,
                                                unsigned short* __restrict__ Wih_bf,
                                                unsigned short* __restrict__ Whh_bf,
                                                float* __restrict__ bc) {
    int idx = blockIdx.x * 256 + threadIdx.x;
    if (idx < N_NODES * D) {
        int i = idx >> 7;
        int c = idx & 127;
        catA[(size_t)i * 256 + 128 + c] = f2bf(h_in[idx]);
    }
    if (idx < N_LAYERS * D * D) Ws_bf[idx] = f2bf(Ws[idx]);
    if (idx < N_LAYERS * 3 * D * D) {
        Wih_bf[idx] = f2bf(Wih[idx]);
        Whh_bf[idx] = f2bf(Whh[idx]);
    }
    if (idx < N_LAYERS * 512) {
        int l = idx >> 9;
        int j = idx & 511;
        const float* bi = bih + (size_t)l * 384;
        const float* bh = bhh + (size_t)l * 384;
        float v;
        if (j < 256) v = bi[j] + bh[j];
        else if (j < 384) v = bi[j];
        else v = bh[j - 128];
        bc[idx] = v;
    }
}

// ---------------- build B_cat2[l][512][256], gate-interleaved columns ----------------
// j' = ch*4 + gate (gate: 0=r, 1=z, 2=i_n, 3=h_n); maps to old j = gate*128 + ch.
__global__ __launch_bounds__(256) void build_bcat(const unsigned short* __restrict__ Wp,
                                                  const unsigned short* __restrict__ Whh,
                                                  unsigned short* __restrict__ Bcat) {
    int idx = blockIdx.x * 256 + threadIdx.x;   // L*512*256
    if (idx >= N_LAYERS * 512 * 256) return;
    int l = idx >> 17;
    int rem = idx & 131071;
    int jp = rem >> 8;
    int k = rem & 255;
    int gate = jp & 3;
    int ch = jp >> 2;
    int j = gate * 128 + ch;
    unsigned short v = 0;
    if (j < 256) {
        v = (k < 128) ? Wp[((size_t)l * 384 + j) * 128 + k]
                      : Whh[((size_t)l * 384 + j) * 128 + (k - 128)];
    } else if (j < 384) {
        v = (k < 128) ? Wp[((size_t)l * 384 + j) * 128 + k] : (unsigned short)0;
    } else {
        v = (k >= 128) ? Whh[((size_t)l * 384 + (j - 128)) * 128 + (k - 128)] : (unsigned short)0;
    }
    Bcat[idx] = v;
}

// ---------------- CSR build ----------------
__global__ __launch_bounds__(256) void hist_dst(const int* __restrict__ dst,
                                                int* __restrict__ deg) {
    int e = blockIdx.x * 256 + threadIdx.x;
    if (e < N_EDGES) atomicAdd(&deg[dst[e]], 1);
}

__global__ __launch_bounds__(256) void block_sum(const int* __restrict__ deg,
                                                 int* __restrict__ bsum) {
    __shared__ int s[256];
    int t = threadIdx.x;
    int i = blockIdx.x * 256 + t;
    s[t] = (i < N_NODES) ? deg[i] : 0;
    __syncthreads();
    for (int o = 128; o > 0; o >>= 1) {
        if (t < o) s[t] += s[t + o];
        __syncthreads();
    }
    if (t == 0) bsum[blockIdx.x] = s[0];
}

__global__ __launch_bounds__(256) void scan_partials(const int* __restrict__ bsum,
                                                     int* __restrict__ boff,
                                                     int* __restrict__ row_ptr) {
    __shared__ int s[256];
    int t = threadIdx.x;
    int v = (t < NBLK_SCAN) ? bsum[t] : 0;
    s[t] = v;
    __syncthreads();
    for (int o = 1; o < 256; o <<= 1) {
        int x = (t >= o) ? s[t - o] : 0;
        __syncthreads();
        s[t] += x;
        __syncthreads();
    }
    if (t < NBLK_SCAN) boff[t] = s[t] - v;   // exclusive
    if (t == 255) row_ptr[N_NODES] = s[255];
}

__global__ __launch_bounds__(256) void scan_final(const int* __restrict__ deg,
                                                  const int* __restrict__ boff,
                                                  int* __restrict__ row_ptr,
                                                  int* __restrict__ pos) {
    __shared__ int s[256];
    int t = threadIdx.x;
    int i = blockIdx.x * 256 + t;
    int v = (i < N_NODES) ? deg[i] : 0;
    s[t] = v;
    __syncthreads();
    for (int o = 1; o < 256; o <<= 1) {
        int x = (t >= o) ? s[t - o] : 0;
        __syncthreads();
        s[t] += x;
        __syncthreads();
    }
    int excl = s[t] - v + boff[blockIdx.x];
    if (i < N_NODES) {
        row_ptr[i] = excl;
        pos[i] = excl;
    }
}

__global__ __launch_bounds__(256) void fill_csr(const int* __restrict__ src,
                                                const int* __restrict__ dst,
                                                int* __restrict__ pos,
                                                int* __restrict__ csr_src) {
    int e = blockIdx.x * 256 + threadIdx.x;
    if (e >= N_EDGES) return;
    int p = atomicAdd(&pos[dst[e]], 1);
    csr_src[p] = src[e];
}

// ---------------- gather: cat[n, 0:128] = sum_{e:dst=n} cat[src[e], 128:256] ----------------
__global__ __launch_bounds__(256) void gather_agg(unsigned short* __restrict__ cat,
                                                  const int* __restrict__ row_ptr,
                                                  const int* __restrict__ csr_src) {
    int t = threadIdx.x;
    int node = blockIdx.x * 16 + (t >> 4);
    int c8 = (t & 15) * 8;
    if (node >= N_NODES) return;
    int b = row_ptr[node];
    int e2 = row_ptr[node + 1];
    float acc0[8] = {}, acc1[8] = {}, acc2[8] = {}, acc3[8] = {};
    int e = b;
    for (; e + 4 <= e2; e += 4) {
        int s0 = csr_src[e];
        int s1 = csr_src[e + 1];
        int s2 = csr_src[e + 2];
        int s3 = csr_src[e + 3];
        bf16x8 v0 = *(const bf16x8*)(cat + (size_t)s0 * 256 + 128 + c8);
        bf16x8 v1 = *(const bf16x8*)(cat + (size_t)s1 * 256 + 128 + c8);
        bf16x8 v2 = *(const bf16x8*)(cat + (size_t)s2 * 256 + 128 + c8);
        bf16x8 v3 = *(const bf16x8*)(cat + (size_t)s3 * 256 + 128 + c8);
        #pragma unroll
        for (int j = 0; j < 8; ++j) {
            acc0[j] += bf2f((unsigned short)v0[j]);
            acc1[j] += bf2f((unsigned short)v1[j]);
            acc2[j] += bf2f((unsigned short)v2[j]);
            acc3[j] += bf2f((unsigned short)v3[j]);
        }
    }
    for (; e < e2; ++e) {
        int s0 = csr_src[e];
        bf16x8 v0 = *(const bf16x8*)(cat + (size_t)s0 * 256 + 128 + c8);
        #pragma unroll
        for (int j = 0; j < 8; ++j) acc0[j] += bf2f((unsigned short)v0[j]);
    }
    bf16x8 ov;
    #pragma unroll
    for (int j = 0; j < 8; ++j) ov[j] = (short)f2bf((acc0[j] + acc1[j]) + (acc2[j] + acc3[j]));
    *(bf16x8*)(cat + (size_t)node * 256 + c8) = ov;
}

// ---------------- generic bf16 MFMA GEMM (used for the tiny W' precompute) ----------------
__global__ __launch_bounds__(256) void gemm_bf16(const unsigned short* __restrict__ A, int Ap,
                                                 const unsigned short* __restrict__ W, int Wp,
                                                 unsigned short* __restrict__ out, int Op,
                                                 int M, int Kd,
                                                 size_t lsA, size_t lsW, size_t lsO) {
    A += (size_t)blockIdx.z * lsA;
    W += (size_t)blockIdx.z * lsW;
    out += (size_t)blockIdx.z * lsO;

    __shared__ unsigned short As[128 * 72];
    __shared__ unsigned short Bs[128 * 72];

    const int tid = threadIdx.x;
    const int i0 = blockIdx.x * 128;
    const int j0 = blockIdx.y * 128;

    const int wave = tid >> 6;
    const int lane = tid & 63;
    const int m16 = lane & 15;
    const int quad = lane >> 4;
    const int mr = (wave & 1) * 64;
    const int nc = (wave >> 1) * 64;

    f32x4 acc[4][4];
    #pragma unroll
    for (int a = 0; a < 4; ++a)
        #pragma unroll
        for (int b = 0; b < 4; ++b)
            acc[a][b] = (f32x4){0.f, 0.f, 0.f, 0.f};

    const int r0 = tid >> 3;
    const int kk = (tid & 7) * 8;

    for (int kc = 0; kc < Kd; kc += 64) {
        if (kc) __syncthreads();
        #pragma unroll
        for (int it = 0; it < 4; ++it) {
            int r = r0 + it * 32;
            int gi_ = i0 + r;
            bf16x8 av = {0, 0, 0, 0, 0, 0, 0, 0};
            if (gi_ < M) av = *(const bf16x8*)(A + (size_t)gi_ * Ap + kc + kk);
            *(bf16x8*)&As[r * 72 + kk] = av;
            *(bf16x8*)&Bs[r * 72 + kk] = *(const bf16x8*)(W + (size_t)(j0 + r) * Wp + kc + kk);
        }
        __syncthreads();

        #pragma unroll
        for (int ks = 0; ks < 64; ks += 32) {
            bf16x8 af[4], bf_[4];
            #pragma unroll
            for (int rt = 0; rt < 4; ++rt)
                af[rt] = *(const bf16x8*)&As[(mr + rt * 16 + m16) * 72 + ks + quad * 8];
            #pragma unroll
            for (int ct = 0; ct < 4; ++ct)
                bf_[ct] = *(const bf16x8*)&Bs[(nc + ct * 16 + m16) * 72 + ks + quad * 8];
            #pragma unroll
            for (int rt = 0; rt < 4; ++rt)
                #pragma unroll
                for (int ct = 0; ct < 4; ++ct)
                    acc[rt][ct] = __builtin_amdgcn_mfma_f32_16x16x32_bf16(
                        af[rt], bf_[ct], acc[rt][ct], 0, 0, 0);
        }
    }

    #pragma unroll
    for (int rt = 0; rt < 4; ++rt) {
        #pragma unroll
        for (int r4 = 0; r4 < 4; ++r4) {
            int i = i0 + mr + rt * 16 + quad * 4 + r4;
            if (i >= M) continue;
            #pragma unroll
            for (int ct = 0; ct < 4; ++ct) {
                int j = j0 + nc + ct * 16 + m16;
                out[(size_t)i * Op + j] = f2bf(acc[rt][ct][r4]);
            }
        }
    }
}

// ---------------- fused GEMM + GRU gates, operand-swapped, coalesced epilogue ----------------
// As = weights (Bcat2 layer [512][256], gate-interleaved j'), Bs = cat node rows.
// Lane reg r4 = gate, so each lane's f32x4 acc = (r,z,i_n,h_n) for one (node, channel).
// h_old is snapped out of the Bs tile during the K-chunk that contains columns 128+ch.
// Output goes through LDS (Lo, reusing As) for 64B-coalesced bf16 stores.
__global__ __launch_bounds__(256) void gemm_gru(const unsigned short* __restrict__ catR,
                                                unsigned short* __restrict__ catW,
                                                const unsigned short* __restrict__ W,
                                                const float* __restrict__ bc) {
    __shared__ unsigned short As[128 * 72];   // weight rows (j'); reused as Lo in epilogue
    __shared__ unsigned short Bs[128 * 72];   // node rows
    unsigned short* Lo = As;                  // [128][40] bf16 out staging (10240 B)

    const int tid = threadIdx.x;
    const int i0 = blockIdx.x * 128;   // node base
    const int j0 = blockIdx.y * 128;   // j' base
    const int ch_base = blockIdx.y * 32;

    const int wave = tid >> 6;
    const int lane = tid & 63;
    const int m16 = lane & 15;
    const int quad = lane >> 4;
    const int mr = (wave & 1) * 64;    // j' sub-tile
    const int nc = (wave >> 1) * 64;   // node sub-tile
    const int chw = ch_base + (wave & 1) * 16;

    // which K-chunk holds columns 128+ch for this block's channels
    const int h_chunk = (ch_base & 64) ? 192 : 128;

    f32x4 acc[4][4];
    #pragma unroll
    for (int a = 0; a < 4; ++a)
        #pragma unroll
        for (int b = 0; b < 4; ++b)
            acc[a][b] = (f32x4){0.f, 0.f, 0.f, 0.f};

    float hold[4][4];

    const int r0 = tid >> 3;
    const int kk = (tid & 7) * 8;

    for (int kc = 0; kc < 256; kc += 64) {
        if (kc) __syncthreads();
        #pragma unroll
        for (int it = 0; it < 4; ++it) {
            int r = r0 + it * 32;
            *(bf16x8*)&As[r * 72 + kk] = *(const bf16x8*)(W + (size_t)(j0 + r) * 256 + kc + kk);
            int gn = i0 + r;
            bf16x8 bv = {0, 0, 0, 0, 0, 0, 0, 0};
            if (gn < N_NODES) bv = *(const bf16x8*)(catR + (size_t)gn * 256 + kc + kk);
            *(bf16x8*)&Bs[r * 72 + kk] = bv;
        }
        __syncthreads();

        if (kc == h_chunk) {
            // snapshot h_old from the staged node rows (LDS, 2-way conflict = free)
            #pragma unroll
            for (int rt = 0; rt < 4; ++rt) {
                int ch = chw + rt * 4 + quad;
                int off = 128 + ch - h_chunk;   // 0..63
                #pragma unroll
                for (int ct = 0; ct < 4; ++ct)
                    hold[rt][ct] = bf2f(Bs[(nc + ct * 16 + m16) * 72 + off]);
            }
        }

        #pragma unroll
        for (int ks = 0; ks < 64; ks += 32) {
            bf16x8 af[4], bf_[4];
            #pragma unroll
            for (int rt = 0; rt < 4; ++rt)
                af[rt] = *(const bf16x8*)&As[(mr + rt * 16 + m16) * 72 + ks + quad * 8];
            #pragma unroll
            for (int ct = 0; ct < 4; ++ct)
                bf_[ct] = *(const bf16x8*)&Bs[(nc + ct * 16 + m16) * 72 + ks + quad * 8];
            #pragma unroll
            for (int rt = 0; rt < 4; ++rt)
                #pragma unroll
                for (int ct = 0; ct < 4; ++ct)
                    acc[rt][ct] = __builtin_amdgcn_mfma_f32_16x16x32_bf16(
                        af[rt], bf_[ct], acc[rt][ct], 0, 0, 0);
        }
    }

    // epilogue: gates straight from accumulators -> Lo (LDS) -> coalesced stores
    __syncthreads();   // all ds_reads of As done before overwrite
    #pragma unroll
    for (int rt = 0; rt < 4; ++rt) {
        int ch = chw + rt * 4 + quad;
        float br  = bc[ch];
        float bz  = bc[128 + ch];
        float bni = bc[256 + ch];
        float bnh = bc[384 + ch];
        int chl = ch - ch_base;   // 0..31
        #pragma unroll
        for (int ct = 0; ct < 4; ++ct) {
            int rloc = nc + ct * 16 + m16;
            float r = 1.f / (1.f + __expf(-(acc[rt][ct][0] + br)));
            float z = 1.f / (1.f + __expf(-(acc[rt][ct][1] + bz)));
            float a = acc[rt][ct][2] + bni + r * (acc[rt][ct][3] + bnh);
            a = fminf(fmaxf(a, -20.f), 20.f);
            float t2 = __expf(2.f * a);
            float n = (t2 - 1.f) / (t2 + 1.f);
            float o = (1.f - z) * n + z * hold[rt][ct];
            o = o > 0.f ? o : 0.f;
            Lo[rloc * 40 + chl] = f2bf(o);
        }
    }
    __syncthreads();
    #pragma unroll
    for (int it = 0; it < 2; ++it) {
        int unit = it * 256 + tid;      // 0..511 = 128 rows x 4 segs
        int row = unit >> 2;
        int seg = (unit & 3) * 8;
        int node = i0 + row;
        if (node < N_NODES)
            *(bf16x8*)(catW + (size_t)node * 256 + 128 + ch_base + seg) =
                *(const bf16x8*)&Lo[row * 40 + seg];
    }
}

// ---------------- mean pool over sorted batch (bf16 h in cat) ----------------
__global__ __launch_bounds__(128) void pool_sorted(const unsigned short* __restrict__ cat,
                                                   const int* __restrict__ batch,
                                                   float* __restrict__ hg) {
    int g = blockIdx.x;
    int c = threadIdx.x;
    int lo = 0, hi = N_NODES;
    while (lo < hi) { int mid = (lo + hi) >> 1; if (batch[mid] < g) lo = mid + 1; else hi = mid; }
    int start = lo;
    lo = start; hi = N_NODES;
    while (lo < hi) { int mid = (lo + hi) >> 1; if (batch[mid] < g + 1) lo = mid + 1; else hi = mid; }
    int end = lo;
    float s = 0.f;
    for (int i = start; i < end; ++i) s += bf2f(cat[(size_t)i * 256 + 128 + c]);
    float cnt = (float)(end - start);
    hg[(size_t)g * D + c] = s / fmaxf(cnt, 1.f);
}

// ---------------- fc1 + elu ----------------
__global__ __launch_bounds__(128) void fc1_elu(const float* __restrict__ hg,
                                               const float* __restrict__ w,
                                               const float* __restrict__ b,
                                               float* __restrict__ z) {
    __shared__ float row[128];
    int g = blockIdx.x;
    int j = threadIdx.x;
    row[j] = hg[(size_t)g * 128 + j];
    __syncthreads();
    float acc = b[j];
    const float* wr = w + (size_t)j * 128;
    #pragma unroll 4
    for (int k = 0; k < 128; ++k) acc += row[k] * wr[k];
    z[(size_t)g * 128 + j] = acc > 0.f ? acc : (expf(acc) - 1.f);
}

// ---------------- fc2 ----------------
__global__ __launch_bounds__(64) void fc2_k(const float* __restrict__ z,
                                            const float* __restrict__ w,
                                            const float* __restrict__ b,
                                            float* __restrict__ logits) {
    __shared__ float row[128];
    int g = blockIdx.x;
    int t = threadIdx.x;
    row[t] = z[(size_t)g * 128 + t];
    row[t + 64] = z[(size_t)g * 128 + 64 + t];
    __syncthreads();
    if (t < N_CLASSES) {
        float acc = b[t];
        const float* wr = w + (size_t)t * 128;
        #pragma unroll 4
        for (int k = 0; k < 128; ++k) acc += row[k] * wr[k];
        logits[(size_t)g * N_CLASSES + t] = acc;
    }
}

// ---------------- log_softmax over axis 0 ----------------
__global__ __launch_bounds__(512) void logsoftmax_axis0(const float* __restrict__ logits,
                                                        float* __restrict__ out) {
    __shared__ float red[512];
    int c = blockIdx.x;
    int g = threadIdx.x;
    float x = logits[(size_t)g * N_CLASSES + c];
    red[g] = x;
    __syncthreads();
    for (int s = 256; s > 0; s >>= 1) {
        if (g < s) red[g] = fmaxf(red[g], red[g + s]);
        __syncthreads();
    }
    float mx = red[0];
    __syncthreads();
    red[g] = expf(x - mx);
    __syncthreads();
    for (int s = 256; s > 0; s >>= 1) {
        if (g < s) red[g] += red[g + s];
        __syncthreads();
    }
    float lse = mx + logf(red[0]);
    out[(size_t)g * N_CLASSES + c] = x - lse;
}

// ---------------- launch ----------------
extern "C" void kernel_launch(void* const* d_in, const int* in_sizes, int n_in,
                              void* d_out, int out_size, void* d_ws, size_t ws_size,
                              hipStream_t stream) {
    const float* h_in   = (const float*)d_in[0];
    const int*   eidx   = (const int*)d_in[1];
    const int*   batch  = (const int*)d_in[3];
    const float* Ws     = (const float*)d_in[4];
    const float* W_ih   = (const float*)d_in[5];
    const float* W_hh   = (const float*)d_in[6];
    const float* b_ih   = (const float*)d_in[7];
    const float* b_hh   = (const float*)d_in[8];
    const float* fc1_w  = (const float*)d_in[9];
    const float* fc1_b  = (const float*)d_in[10];
    const float* fc2_w  = (const float*)d_in[11];
    const float* fc2_b  = (const float*)d_in[12];
    float* out = (float*)d_out;

    char* ws = (char*)d_ws;
    size_t off = 0;
    auto alloc = [&](size_t bytes) {
        void* p = ws + off;
        off += (bytes + 255) & ~(size_t)255;
        return p;
    };
    unsigned short* catA = (unsigned short*)alloc((size_t)N_NODES * 256 * 2);  // [agg | h] bf16
    unsigned short* catB = (unsigned short*)alloc((size_t)N_NODES * 256 * 2);
    unsigned short* Ws_bf  = (unsigned short*)alloc((size_t)N_LAYERS * D * D * 2);
    unsigned short* Wih_bf = (unsigned short*)alloc((size_t)N_LAYERS * 3 * D * D * 2);
    unsigned short* Whh_bf = (unsigned short*)alloc((size_t)N_LAYERS * 3 * D * D * 2);
    unsigned short* Wp_bf  = (unsigned short*)alloc((size_t)N_LAYERS * 3 * D * D * 2);  // Wih @ Ws^T
    unsigned short* Bcat   = (unsigned short*)alloc((size_t)N_LAYERS * 512 * 256 * 2);
    float* bc   = (float*)alloc((size_t)N_LAYERS * 512 * 4);
    float* hg   = (float*)alloc((size_t)N_GRAPHS * D * 4);
    float* zb   = (float*)alloc((size_t)N_GRAPHS * D * 4);
    float* lgts = (float*)alloc((size_t)N_GRAPHS * N_CLASSES * 4);
    int* deg     = (int*)alloc((size_t)N_NODES * 4);
    int* row_ptr = (int*)alloc((size_t)(N_NODES + 1) * 4);
    int* pos     = (int*)alloc((size_t)N_NODES * 4);
    int* csr_src = (int*)alloc((size_t)N_EDGES * 4);
    int* bsum    = (int*)alloc((size_t)NBLK_SCAN * 4);
    int* boff    = (int*)alloc((size_t)NBLK_SCAN * 4);

    const int* src = eidx;
    const int* dst = eidx + N_EDGES;

    init_all<<<(N_NODES * D + 255) / 256, 256, 0, stream>>>(
        h_in, Ws, W_ih, W_hh, b_ih, b_hh, catA, Ws_bf, Wih_bf, Whh_bf, bc);

    // W'_l = Wih_l @ Ws_l^T, batched over layers via grid.z
    gemm_bf16<<<dim3(3, 1, N_LAYERS), 256, 0, stream>>>(
        Wih_bf, 128, Ws_bf, 128, Wp_bf, 128, 384, 128,
        (size_t)384 * 128, (size_t)128 * 128, (size_t)384 * 128);
    build_bcat<<<(N_LAYERS * 512 * 256 + 255) / 256, 256, 0, stream>>>(Wp_bf, Whh_bf, Bcat);

    // CSR build (edges static) — distributed scan
    fill_zero4<<<(N_NODES / 4 + 255) / 256, 256, 0, stream>>>((float4*)deg, N_NODES / 4);
    hist_dst<<<(N_EDGES + 255) / 256, 256, 0, stream>>>(dst, deg);
    block_sum<<<NBLK_SCAN, 256, 0, stream>>>(deg, bsum);
    scan_partials<<<1, 256, 0, stream>>>(bsum, boff, row_ptr);
    scan_final<<<NBLK_SCAN, 256, 0, stream>>>(deg, boff, row_ptr, pos);
    fill_csr<<<(N_EDGES + 255) / 256, 256, 0, stream>>>(src, dst, pos, csr_src);

    const int mtiles = (N_NODES + 127) / 128;   // 391
    for (int l = 0; l < N_LAYERS; ++l) {
        unsigned short* catR = (l & 1) ? catB : catA;
        unsigned short* catW = (l & 1) ? catA : catB;
        // catR[:,0:128] = gather of catR[:,128:256]  (agg of h)
        gather_agg<<<(N_NODES + 15) / 16, 256, 0, stream>>>(catR, row_ptr, csr_src);
        // fused: gates(catR @ Bcat2_l^T) -> catW[:,128:256] (new h, bf16)
        gemm_gru<<<dim3(mtiles, 4), 256, 0, stream>>>(
            catR, catW, Bcat + (size_t)l * 512 * 256, bc + (size_t)l * 512);
    }

    // after 4 layers (even), final h lives in catA[:,128:256]
    pool_sorted<<<N_GRAPHS, 128, 0, stream>>>(catA, batch, hg);
    fc1_elu<<<N_GRAPHS, 128, 0, stream>>>(hg, fc1_w, fc1_b, zb);
    fc2_k<<<N_GRAPHS, 64, 0, stream>>>(zb, fc2_w, fc2_b, lgts);
    logsoftmax_axis0<<<N_CLASSES, 512, 0, stream>>>(lgts, out);
}

// Round 10
// 461.561 us; speedup vs baseline: 1.1456x; 1.1155x over previous
//
#include <hip/hip_runtime.h>
#include <math.h>

#define N_NODES 50000
#define N_EDGES 600000
#define D 128
#define N_GRAPHS 512
#define N_CLASSES 10
#define N_LAYERS 4
#define NBLK_SCAN 196   // ceil(50000/256)

typedef __attribute__((ext_vector_type(8))) short bf16x8;
typedef __attribute__((ext_vector_type(4))) float f32x4;

__device__ inline unsigned short f2bf(float f) {
    union { float f; unsigned int u; } v; v.f = f;
    unsigned int r = (v.u + 0x7fffu + ((v.u >> 16) & 1u)) >> 16;
    return (unsigned short)r;
}
__device__ inline float bf2f(unsigned short u) {
    union { unsigned int u; float f; } v; v.u = ((unsigned int)u) << 16;
    return v.f;
}

// async global -> LDS, 16B per lane; LDS dest = wave-uniform base + lane*16
typedef __attribute__((address_space(1))) const void GV;
typedef __attribute__((address_space(3))) void LV;
__device__ __forceinline__ void dma16(const void* g, void* l) {
    __builtin_amdgcn_global_load_lds((GV*)g, (LV*)l, 16, 0, 0);
}

// ---------------- zero fill ----------------
__global__ __launch_bounds__(256) void fill_zero4(float4* p, int n4) {
    int i = blockIdx.x * 256 + threadIdx.x;
    if (i < n4) p[i] = make_float4(0.f, 0.f, 0.f, 0.f);
}

// ---------------- fused init: h bf16 into catA[:,128:] + weight bf16 + combined bias ----------------
// bc layout [L][512]: j<128: bih_r+bhh_r ; 128..256: bih_z+bhh_z ; 256..384: bih_n ; 384..512: bhh_n
__global__ __launch_bounds__(256) void init_all(const float* __restrict__ h_in,
                                                const float* __restrict__ Ws,
                                                const float* __restrict__ Wih,
                                                const float* __restrict__ Whh,
                                                const float* __restrict__ bih,
                                                const float* __restrict__ bhh,
                                                unsigned short* __restrict__ catA,
                                                unsigned short* __restrict__ Ws_bf,
                                                unsigned short* __restrict__ Wih_bf,
                                                unsigned short* __restrict__ Whh_bf,
                                                float* __restrict__ bc) {
    int idx = blockIdx.x * 256 + threadIdx.x;
    if (idx < N_NODES * D) {
        int i = idx >> 7;
        int c = idx & 127;
        catA[(size_t)i * 256 + 128 + c] = f2bf(h_in[idx]);
    }
    if (idx < N_LAYERS * D * D) Ws_bf[idx] = f2bf(Ws[idx]);
    if (idx < N_LAYERS * 3 * D * D) {
        Wih_bf[idx] = f2bf(Wih[idx]);
        Whh_bf[idx] = f2bf(Whh[idx]);
    }
    if (idx < N_LAYERS * 512) {
        int l = idx >> 9;
        int j = idx & 511;
        const float* bi = bih + (size_t)l * 384;
        const float* bh = bhh + (size_t)l * 384;
        float v;
        if (j < 256) v = bi[j] + bh[j];
        else if (j < 384) v = bi[j];
        else v = bh[j - 128];
        bc[idx] = v;
    }
}

// ---------------- build B_cat2[l][512][256], gate-interleaved columns ----------------
// j' = ch*4 + gate (gate: 0=r, 1=z, 2=i_n, 3=h_n); maps to old j = gate*128 + ch.
__global__ __launch_bounds__(256) void build_bcat(const unsigned short* __restrict__ Wp,
                                                  const unsigned short* __restrict__ Whh,
                                                  unsigned short* __restrict__ Bcat) {
    int idx = blockIdx.x * 256 + threadIdx.x;   // L*512*256
    if (idx >= N_LAYERS * 512 * 256) return;
    int l = idx >> 17;
    int rem = idx & 131071;
    int jp = rem >> 8;
    int k = rem & 255;
    int gate = jp & 3;
    int ch = jp >> 2;
    int j = gate * 128 + ch;
    unsigned short v = 0;
    if (j < 256) {
        v = (k < 128) ? Wp[((size_t)l * 384 + j) * 128 + k]
                      : Whh[((size_t)l * 384 + j) * 128 + (k - 128)];
    } else if (j < 384) {
        v = (k < 128) ? Wp[((size_t)l * 384 + j) * 128 + k] : (unsigned short)0;
    } else {
        v = (k >= 128) ? Whh[((size_t)l * 384 + (j - 128)) * 128 + (k - 128)] : (unsigned short)0;
    }
    Bcat[idx] = v;
}

// ---------------- CSR build ----------------
__global__ __launch_bounds__(256) void hist_dst(const int* __restrict__ dst,
                                                int* __restrict__ deg) {
    int e = blockIdx.x * 256 + threadIdx.x;
    if (e < N_EDGES) atomicAdd(&deg[dst[e]], 1);
}

__global__ __launch_bounds__(256) void block_sum(const int* __restrict__ deg,
                                                 int* __restrict__ bsum) {
    __shared__ int s[256];
    int t = threadIdx.x;
    int i = blockIdx.x * 256 + t;
    s[t] = (i < N_NODES) ? deg[i] : 0;
    __syncthreads();
    for (int o = 128; o > 0; o >>= 1) {
        if (t < o) s[t] += s[t + o];
        __syncthreads();
    }
    if (t == 0) bsum[blockIdx.x] = s[0];
}

__global__ __launch_bounds__(256) void scan_partials(const int* __restrict__ bsum,
                                                     int* __restrict__ boff,
                                                     int* __restrict__ row_ptr) {
    __shared__ int s[256];
    int t = threadIdx.x;
    int v = (t < NBLK_SCAN) ? bsum[t] : 0;
    s[t] = v;
    __syncthreads();
    for (int o = 1; o < 256; o <<= 1) {
        int x = (t >= o) ? s[t - o] : 0;
        __syncthreads();
        s[t] += x;
        __syncthreads();
    }
    if (t < NBLK_SCAN) boff[t] = s[t] - v;   // exclusive
    if (t == 255) row_ptr[N_NODES] = s[255];
}

__global__ __launch_bounds__(256) void scan_final(const int* __restrict__ deg,
                                                  const int* __restrict__ boff,
                                                  int* __restrict__ row_ptr,
                                                  int* __restrict__ pos) {
    __shared__ int s[256];
    int t = threadIdx.x;
    int i = blockIdx.x * 256 + t;
    int v = (i < N_NODES) ? deg[i] : 0;
    s[t] = v;
    __syncthreads();
    for (int o = 1; o < 256; o <<= 1) {
        int x = (t >= o) ? s[t - o] : 0;
        __syncthreads();
        s[t] += x;
        __syncthreads();
    }
    int excl = s[t] - v + boff[blockIdx.x];
    if (i < N_NODES) {
        row_ptr[i] = excl;
        pos[i] = excl;
    }
}

__global__ __launch_bounds__(256) void fill_csr(const int* __restrict__ src,
                                                const int* __restrict__ dst,
                                                int* __restrict__ pos,
                                                int* __restrict__ csr_src) {
    int e = blockIdx.x * 256 + threadIdx.x;
    if (e >= N_EDGES) return;
    int p = atomicAdd(&pos[dst[e]], 1);
    csr_src[p] = src[e];
}

// ---------------- gather: cat[n, 0:128] = sum_{e:dst=n} cat[src[e], 128:256] ----------------
__global__ __launch_bounds__(256) void gather_agg(unsigned short* __restrict__ cat,
                                                  const int* __restrict__ row_ptr,
                                                  const int* __restrict__ csr_src) {
    int t = threadIdx.x;
    int node = blockIdx.x * 16 + (t >> 4);
    int c8 = (t & 15) * 8;
    if (node >= N_NODES) return;
    int b = row_ptr[node];
    int e2 = row_ptr[node + 1];
    float acc0[8] = {}, acc1[8] = {}, acc2[8] = {}, acc3[8] = {};
    int e = b;
    for (; e + 4 <= e2; e += 4) {
        int s0 = csr_src[e];
        int s1 = csr_src[e + 1];
        int s2 = csr_src[e + 2];
        int s3 = csr_src[e + 3];
        bf16x8 v0 = *(const bf16x8*)(cat + (size_t)s0 * 256 + 128 + c8);
        bf16x8 v1 = *(const bf16x8*)(cat + (size_t)s1 * 256 + 128 + c8);
        bf16x8 v2 = *(const bf16x8*)(cat + (size_t)s2 * 256 + 128 + c8);
        bf16x8 v3 = *(const bf16x8*)(cat + (size_t)s3 * 256 + 128 + c8);
        #pragma unroll
        for (int j = 0; j < 8; ++j) {
            acc0[j] += bf2f((unsigned short)v0[j]);
            acc1[j] += bf2f((unsigned short)v1[j]);
            acc2[j] += bf2f((unsigned short)v2[j]);
            acc3[j] += bf2f((unsigned short)v3[j]);
        }
    }
    for (; e < e2; ++e) {
        int s0 = csr_src[e];
        bf16x8 v0 = *(const bf16x8*)(cat + (size_t)s0 * 256 + 128 + c8);
        #pragma unroll
        for (int j = 0; j < 8; ++j) acc0[j] += bf2f((unsigned short)v0[j]);
    }
    bf16x8 ov;
    #pragma unroll
    for (int j = 0; j < 8; ++j) ov[j] = (short)f2bf((acc0[j] + acc1[j]) + (acc2[j] + acc3[j]));
    *(bf16x8*)(cat + (size_t)node * 256 + c8) = ov;
}

// ---------------- generic bf16 MFMA GEMM (used for the tiny W' precompute) ----------------
__global__ __launch_bounds__(256) void gemm_bf16(const unsigned short* __restrict__ A, int Ap,
                                                 const unsigned short* __restrict__ W, int Wp,
                                                 unsigned short* __restrict__ out, int Op,
                                                 int M, int Kd,
                                                 size_t lsA, size_t lsW, size_t lsO) {
    A += (size_t)blockIdx.z * lsA;
    W += (size_t)blockIdx.z * lsW;
    out += (size_t)blockIdx.z * lsO;

    __shared__ unsigned short As[128 * 72];
    __shared__ unsigned short Bs[128 * 72];

    const int tid = threadIdx.x;
    const int i0 = blockIdx.x * 128;
    const int j0 = blockIdx.y * 128;

    const int wave = tid >> 6;
    const int lane = tid & 63;
    const int m16 = lane & 15;
    const int quad = lane >> 4;
    const int mr = (wave & 1) * 64;
    const int nc = (wave >> 1) * 64;

    f32x4 acc[4][4];
    #pragma unroll
    for (int a = 0; a < 4; ++a)
        #pragma unroll
        for (int b = 0; b < 4; ++b)
            acc[a][b] = (f32x4){0.f, 0.f, 0.f, 0.f};

    const int r0 = tid >> 3;
    const int kk = (tid & 7) * 8;

    for (int kc = 0; kc < Kd; kc += 64) {
        if (kc) __syncthreads();
        #pragma unroll
        for (int it = 0; it < 4; ++it) {
            int r = r0 + it * 32;
            int gi_ = i0 + r;
            bf16x8 av = {0, 0, 0, 0, 0, 0, 0, 0};
            if (gi_ < M) av = *(const bf16x8*)(A + (size_t)gi_ * Ap + kc + kk);
            *(bf16x8*)&As[r * 72 + kk] = av;
            *(bf16x8*)&Bs[r * 72 + kk] = *(const bf16x8*)(W + (size_t)(j0 + r) * Wp + kc + kk);
        }
        __syncthreads();

        #pragma unroll
        for (int ks = 0; ks < 64; ks += 32) {
            bf16x8 af[4], bf_[4];
            #pragma unroll
            for (int rt = 0; rt < 4; ++rt)
                af[rt] = *(const bf16x8*)&As[(mr + rt * 16 + m16) * 72 + ks + quad * 8];
            #pragma unroll
            for (int ct = 0; ct < 4; ++ct)
                bf_[ct] = *(const bf16x8*)&Bs[(nc + ct * 16 + m16) * 72 + ks + quad * 8];
            #pragma unroll
            for (int rt = 0; rt < 4; ++rt)
                #pragma unroll
                for (int ct = 0; ct < 4; ++ct)
                    acc[rt][ct] = __builtin_amdgcn_mfma_f32_16x16x32_bf16(
                        af[rt], bf_[ct], acc[rt][ct], 0, 0, 0);
        }
    }

    #pragma unroll
    for (int rt = 0; rt < 4; ++rt) {
        #pragma unroll
        for (int r4 = 0; r4 < 4; ++r4) {
            int i = i0 + mr + rt * 16 + quad * 4 + r4;
            if (i >= M) continue;
            #pragma unroll
            for (int ct = 0; ct < 4; ++ct) {
                int j = j0 + nc + ct * 16 + m16;
                out[(size_t)i * Op + j] = f2bf(acc[rt][ct][r4]);
            }
        }
    }
}

// ---------------- fused GEMM + GRU gates: async LDS staging + XOR-swizzled layout ----------------
// As = weights (Bcat2 layer [512][256], gate-interleaved j'), Bs = cat node rows.
// Tiles stored pitch-64 (no pad) with 16B-chunk swizzle: slot s = c ^ (row&7).
// Staged via global_load_lds (16B/lane, no VGPR round-trip). Lane reg r4 = gate.
// h_old snapped from Bs during the chunk holding cols 128+ch. Coalesced out via Lo.
__global__ __launch_bounds__(256) void gemm_gru(const unsigned short* __restrict__ catR,
                                                unsigned short* __restrict__ catW,
                                                const unsigned short* __restrict__ W,
                                                const float* __restrict__ bc) {
    __shared__ unsigned short As[128 * 64];   // weight tile; reused as Lo in epilogue
    __shared__ unsigned short Bs[128 * 64];   // node tile
    unsigned short* Lo = As;                  // [128][40] bf16 out staging (10240 B)

    const int tid = threadIdx.x;
    const int i0 = blockIdx.x * 128;   // node base
    const int j0 = blockIdx.y * 128;   // j' base
    const int ch_base = blockIdx.y * 32;

    const int wave = tid >> 6;
    const int lane = tid & 63;
    const int m16 = lane & 15;
    const int quad = lane >> 4;
    const int mr = (wave & 1) * 64;    // j' sub-tile
    const int nc = (wave >> 1) * 64;   // node sub-tile
    const int chw = ch_base + (wave & 1) * 16;

    // staging geometry: lane covers row rb = lane>>3, swizzled chunk (lane&7)^rb
    const int rb = lane >> 3;                       // 0..7
    const int cswz = (((lane & 7) ^ rb) * 8);       // ushort offset of fetched chunk

    // which K-chunk holds columns 128+ch for this block's channels
    const int h_chunk = (ch_base & 64) ? 192 : 128;

    f32x4 acc[4][4];
    #pragma unroll
    for (int a = 0; a < 4; ++a)
        #pragma unroll
        for (int b = 0; b < 4; ++b)
            acc[a][b] = (f32x4){0.f, 0.f, 0.f, 0.f};

    float hold[4][4];

    for (int kc = 0; kc < 256; kc += 64) {
        if (kc) __syncthreads();
        #pragma unroll
        for (int it = 0; it < 4; ++it) {
            int rowbase = it * 32 + wave * 8;          // wave-uniform
            int row = rowbase + rb;
            dma16(W + (size_t)(j0 + row) * 256 + kc + cswz, &As[rowbase * 64]);
            int gn = i0 + row;
            if (gn < N_NODES)
                dma16(catR + (size_t)gn * 256 + kc + cswz, &Bs[rowbase * 64]);
        }
        __syncthreads();   // drains vmcnt (compiler inserts) -> tiles ready

        if (kc == h_chunk) {
            // snapshot h_old from staged node rows (swizzled LDS indexing)
            #pragma unroll
            for (int rt = 0; rt < 4; ++rt) {
                int ch = chw + rt * 4 + quad;
                int off = 128 + ch - h_chunk;   // 0..63 ushort within chunk
                #pragma unroll
                for (int ct = 0; ct < 4; ++ct) {
                    int row = nc + ct * 16 + m16;
                    int idx = row * 64 + (((off >> 3) ^ (row & 7)) * 8) + (off & 7);
                    hold[rt][ct] = bf2f(Bs[idx]);
                }
            }
        }

        #pragma unroll
        for (int ks = 0; ks < 64; ks += 32) {
            const int cbase = (ks >> 3) + quad;   // logical 16B chunk index
            bf16x8 af[4], bf_[4];
            #pragma unroll
            for (int rt = 0; rt < 4; ++rt) {
                int row = mr + rt * 16 + m16;
                af[rt] = *(const bf16x8*)&As[row * 64 + ((cbase ^ (row & 7)) * 8)];
            }
            #pragma unroll
            for (int ct = 0; ct < 4; ++ct) {
                int row = nc + ct * 16 + m16;
                bf_[ct] = *(const bf16x8*)&Bs[row * 64 + ((cbase ^ (row & 7)) * 8)];
            }
            #pragma unroll
            for (int rt = 0; rt < 4; ++rt)
                #pragma unroll
                for (int ct = 0; ct < 4; ++ct)
                    acc[rt][ct] = __builtin_amdgcn_mfma_f32_16x16x32_bf16(
                        af[rt], bf_[ct], acc[rt][ct], 0, 0, 0);
        }
    }

    // epilogue: gates straight from accumulators -> Lo (LDS) -> coalesced stores
    __syncthreads();   // all ds_reads of As done before overwrite
    #pragma unroll
    for (int rt = 0; rt < 4; ++rt) {
        int ch = chw + rt * 4 + quad;
        float br  = bc[ch];
        float bz  = bc[128 + ch];
        float bni = bc[256 + ch];
        float bnh = bc[384 + ch];
        int chl = ch - ch_base;   // 0..31
        #pragma unroll
        for (int ct = 0; ct < 4; ++ct) {
            int rloc = nc + ct * 16 + m16;
            float r = 1.f / (1.f + __expf(-(acc[rt][ct][0] + br)));
            float z = 1.f / (1.f + __expf(-(acc[rt][ct][1] + bz)));
            float a = acc[rt][ct][2] + bni + r * (acc[rt][ct][3] + bnh);
            a = fminf(fmaxf(a, -20.f), 20.f);
            float t2 = __expf(2.f * a);
            float n = (t2 - 1.f) / (t2 + 1.f);
            float o = (1.f - z) * n + z * hold[rt][ct];
            o = o > 0.f ? o : 0.f;
            Lo[rloc * 40 + chl] = f2bf(o);
        }
    }
    __syncthreads();
    #pragma unroll
    for (int it = 0; it < 2; ++it) {
        int unit = it * 256 + tid;      // 0..511 = 128 rows x 4 segs
        int row = unit >> 2;
        int seg = (unit & 3) * 8;
        int node = i0 + row;
        if (node < N_NODES)
            *(bf16x8*)(catW + (size_t)node * 256 + 128 + ch_base + seg) =
                *(const bf16x8*)&Lo[row * 40 + seg];
    }
}

// ---------------- mean pool over sorted batch (bf16 h in cat) ----------------
__global__ __launch_bounds__(128) void pool_sorted(const unsigned short* __restrict__ cat,
                                                   const int* __restrict__ batch,
                                                   float* __restrict__ hg) {
    int g = blockIdx.x;
    int c = threadIdx.x;
    int lo = 0, hi = N_NODES;
    while (lo < hi) { int mid = (lo + hi) >> 1; if (batch[mid] < g) lo = mid + 1; else hi = mid; }
    int start = lo;
    lo = start; hi = N_NODES;
    while (lo < hi) { int mid = (lo + hi) >> 1; if (batch[mid] < g + 1) lo = mid + 1; else hi = mid; }
    int end = lo;
    float s = 0.f;
    for (int i = start; i < end; ++i) s += bf2f(cat[(size_t)i * 256 + 128 + c]);
    float cnt = (float)(end - start);
    hg[(size_t)g * D + c] = s / fmaxf(cnt, 1.f);
}

// ---------------- fc1 + elu ----------------
__global__ __launch_bounds__(128) void fc1_elu(const float* __restrict__ hg,
                                               const float* __restrict__ w,
                                               const float* __restrict__ b,
                                               float* __restrict__ z) {
    __shared__ float row[128];
    int g = blockIdx.x;
    int j = threadIdx.x;
    row[j] = hg[(size_t)g * 128 + j];
    __syncthreads();
    float acc = b[j];
    const float* wr = w + (size_t)j * 128;
    #pragma unroll 4
    for (int k = 0; k < 128; ++k) acc += row[k] * wr[k];
    z[(size_t)g * 128 + j] = acc > 0.f ? acc : (expf(acc) - 1.f);
}

// ---------------- fc2 ----------------
__global__ __launch_bounds__(64) void fc2_k(const float* __restrict__ z,
                                            const float* __restrict__ w,
                                            const float* __restrict__ b,
                                            float* __restrict__ logits) {
    __shared__ float row[128];
    int g = blockIdx.x;
    int t = threadIdx.x;
    row[t] = z[(size_t)g * 128 + t];
    row[t + 64] = z[(size_t)g * 128 + 64 + t];
    __syncthreads();
    if (t < N_CLASSES) {
        float acc = b[t];
        const float* wr = w + (size_t)t * 128;
        #pragma unroll 4
        for (int k = 0; k < 128; ++k) acc += row[k] * wr[k];
        logits[(size_t)g * N_CLASSES + t] = acc;
    }
}

// ---------------- log_softmax over axis 0 ----------------
__global__ __launch_bounds__(512) void logsoftmax_axis0(const float* __restrict__ logits,
                                                        float* __restrict__ out) {
    __shared__ float red[512];
    int c = blockIdx.x;
    int g = threadIdx.x;
    float x = logits[(size_t)g * N_CLASSES + c];
    red[g] = x;
    __syncthreads();
    for (int s = 256; s > 0; s >>= 1) {
        if (g < s) red[g] = fmaxf(red[g], red[g + s]);
        __syncthreads();
    }
    float mx = red[0];
    __syncthreads();
    red[g] = expf(x - mx);
    __syncthreads();
    for (int s = 256; s > 0; s >>= 1) {
        if (g < s) red[g] += red[g + s];
        __syncthreads();
    }
    float lse = mx + logf(red[0]);
    out[(size_t)g * N_CLASSES + c] = x - lse;
}

// ---------------- launch ----------------
extern "C" void kernel_launch(void* const* d_in, const int* in_sizes, int n_in,
                              void* d_out, int out_size, void* d_ws, size_t ws_size,
                              hipStream_t stream) {
    const float* h_in   = (const float*)d_in[0];
    const int*   eidx   = (const int*)d_in[1];
    const int*   batch  = (const int*)d_in[3];
    const float* Ws     = (const float*)d_in[4];
    const float* W_ih   = (const float*)d_in[5];
    const float* W_hh   = (const float*)d_in[6];
    const float* b_ih   = (const float*)d_in[7];
    const float* b_hh   = (const float*)d_in[8];
    const float* fc1_w  = (const float*)d_in[9];
    const float* fc1_b  = (const float*)d_in[10];
    const float* fc2_w  = (const float*)d_in[11];
    const float* fc2_b  = (const float*)d_in[12];
    float* out = (float*)d_out;

    char* ws = (char*)d_ws;
    size_t off = 0;
    auto alloc = [&](size_t bytes) {
        void* p = ws + off;
        off += (bytes + 255) & ~(size_t)255;
        return p;
    };
    unsigned short* catA = (unsigned short*)alloc((size_t)N_NODES * 256 * 2);  // [agg | h] bf16
    unsigned short* catB = (unsigned short*)alloc((size_t)N_NODES * 256 * 2);
    unsigned short* Ws_bf  = (unsigned short*)alloc((size_t)N_LAYERS * D * D * 2);
    unsigned short* Wih_bf = (unsigned short*)alloc((size_t)N_LAYERS * 3 * D * D * 2);
    unsigned short* Whh_bf = (unsigned short*)alloc((size_t)N_LAYERS * 3 * D * D * 2);
    unsigned short* Wp_bf  = (unsigned short*)alloc((size_t)N_LAYERS * 3 * D * D * 2);  // Wih @ Ws^T
    unsigned short* Bcat   = (unsigned short*)alloc((size_t)N_LAYERS * 512 * 256 * 2);
    float* bc   = (float*)alloc((size_t)N_LAYERS * 512 * 4);
    float* hg   = (float*)alloc((size_t)N_GRAPHS * D * 4);
    float* zb   = (float*)alloc((size_t)N_GRAPHS * D * 4);
    float* lgts = (float*)alloc((size_t)N_GRAPHS * N_CLASSES * 4);
    int* deg     = (int*)alloc((size_t)N_NODES * 4);
    int* row_ptr = (int*)alloc((size_t)(N_NODES + 1) * 4);
    int* pos     = (int*)alloc((size_t)N_NODES * 4);
    int* csr_src = (int*)alloc((size_t)N_EDGES * 4);
    int* bsum    = (int*)alloc((size_t)NBLK_SCAN * 4);
    int* boff    = (int*)alloc((size_t)NBLK_SCAN * 4);

    const int* src = eidx;
    const int* dst = eidx + N_EDGES;

    init_all<<<(N_NODES * D + 255) / 256, 256, 0, stream>>>(
        h_in, Ws, W_ih, W_hh, b_ih, b_hh, catA, Ws_bf, Wih_bf, Whh_bf, bc);

    // W'_l = Wih_l @ Ws_l^T, batched over layers via grid.z
    gemm_bf16<<<dim3(3, 1, N_LAYERS), 256, 0, stream>>>(
        Wih_bf, 128, Ws_bf, 128, Wp_bf, 128, 384, 128,
        (size_t)384 * 128, (size_t)128 * 128, (size_t)384 * 128);
    build_bcat<<<(N_LAYERS * 512 * 256 + 255) / 256, 256, 0, stream>>>(Wp_bf, Whh_bf, Bcat);

    // CSR build (edges static) — distributed scan
    fill_zero4<<<(N_NODES / 4 + 255) / 256, 256, 0, stream>>>((float4*)deg, N_NODES / 4);
    hist_dst<<<(N_EDGES + 255) / 256, 256, 0, stream>>>(dst, deg);
    block_sum<<<NBLK_SCAN, 256, 0, stream>>>(deg, bsum);
    scan_partials<<<1, 256, 0, stream>>>(bsum, boff, row_ptr);
    scan_final<<<NBLK_SCAN, 256, 0, stream>>>(deg, boff, row_ptr, pos);
    fill_csr<<<(N_EDGES + 255) / 256, 256, 0, stream>>>(src, dst, pos, csr_src);

    const int mtiles = (N_NODES + 127) / 128;   // 391
    for (int l = 0; l < N_LAYERS; ++l) {
        unsigned short* catR = (l & 1) ? catB : catA;
        unsigned short* catW = (l & 1) ? catA : catB;
        // catR[:,0:128] = gather of catR[:,128:256]  (agg of h)
        gather_agg<<<(N_NODES + 15) / 16, 256, 0, stream>>>(catR, row_ptr, csr_src);
        // fused: gates(catR @ Bcat2_l^T) -> catW[:,128:256] (new h, bf16)
        gemm_gru<<<dim3(mtiles, 4), 256, 0, stream>>>(
            catR, catW, Bcat + (size_t)l * 512 * 256, bc + (size_t)l * 512);
    }

    // after 4 layers (even), final h lives in catA[:,128:256]
    pool_sorted<<<N_GRAPHS, 128, 0, stream>>>(catA, batch, hg);
    fc1_elu<<<N_GRAPHS, 128, 0, stream>>>(hg, fc1_w, fc1_b, zb);
    fc2_k<<<N_GRAPHS, 64, 0, stream>>>(zb, fc2_w, fc2_b, lgts);
    logsoftmax_axis0<<<N_CLASSES, 512, 0, stream>>>(lgts, out);
}

// Round 11
// 431.236 us; speedup vs baseline: 1.2262x; 1.0703x over previous
//
#include <hip/hip_runtime.h>
#include <math.h>

#define N_NODES 50000
#define N_EDGES 600000
#define D 128
#define N_GRAPHS 512
#define N_CLASSES 10
#define N_LAYERS 4
#define NBLK_SCAN 196   // ceil(50000/256)

typedef __attribute__((ext_vector_type(8))) short bf16x8;
typedef __attribute__((ext_vector_type(4))) float f32x4;

__device__ inline unsigned short f2bf(float f) {
    union { float f; unsigned int u; } v; v.f = f;
    unsigned int r = (v.u + 0x7fffu + ((v.u >> 16) & 1u)) >> 16;
    return (unsigned short)r;
}
__device__ inline float bf2f(unsigned short u) {
    union { unsigned int u; float f; } v; v.u = ((unsigned int)u) << 16;
    return v.f;
}

// async global -> LDS, 16B per lane; LDS dest = wave-uniform base + lane*16
typedef __attribute__((address_space(1))) const void GV;
typedef __attribute__((address_space(3))) void LV;
__device__ __forceinline__ void dma16(const void* g, void* l) {
    __builtin_amdgcn_global_load_lds((GV*)g, (LV*)l, 16, 0, 0);
}

// ---------------- zero fill ----------------
__global__ __launch_bounds__(256) void fill_zero4(float4* p, int n4) {
    int i = blockIdx.x * 256 + threadIdx.x;
    if (i < n4) p[i] = make_float4(0.f, 0.f, 0.f, 0.f);
}

// ---------------- fused init: h bf16 into catA[:,128:] + weight bf16 + combined bias ----------------
// bc layout [L][512]: j<128: bih_r+bhh_r ; 128..256: bih_z+bhh_z ; 256..384: bih_n ; 384..512: bhh_n
__global__ __launch_bounds__(256) void init_all(const float* __restrict__ h_in,
                                                const float* __restrict__ Ws,
                                                const float* __restrict__ Wih,
                                                const float* __restrict__ Whh,
                                                const float* __restrict__ bih,
                                                const float* __restrict__ bhh,
                                                unsigned short* __restrict__ catA,
                                                unsigned short* __restrict__ Ws_bf,
                                                unsigned short* __restrict__ Wih_bf,
                                                unsigned short* __restrict__ Whh_bf,
                                                float* __restrict__ bc) {
    int idx = blockIdx.x * 256 + threadIdx.x;
    if (idx < N_NODES * D) {
        int i = idx >> 7;
        int c = idx & 127;
        catA[(size_t)i * 256 + 128 + c] = f2bf(h_in[idx]);
    }
    if (idx < N_LAYERS * D * D) Ws_bf[idx] = f2bf(Ws[idx]);
    if (idx < N_LAYERS * 3 * D * D) {
        Wih_bf[idx] = f2bf(Wih[idx]);
        Whh_bf[idx] = f2bf(Whh[idx]);
    }
    if (idx < N_LAYERS * 512) {
        int l = idx >> 9;
        int j = idx & 511;
        const float* bi = bih + (size_t)l * 384;
        const float* bh = bhh + (size_t)l * 384;
        float v;
        if (j < 256) v = bi[j] + bh[j];
        else if (j < 384) v = bi[j];
        else v = bh[j - 128];
        bc[idx] = v;
    }
}

// ---------------- graph bounds: goff[g] = lower_bound(batch, g); goff[512] = N ----------------
__global__ __launch_bounds__(512) void graph_bounds(const int* __restrict__ batch,
                                                    int* __restrict__ goff) {
    int g = threadIdx.x;
    int lo = 0, hi = N_NODES;
    while (lo < hi) { int mid = (lo + hi) >> 1; if (batch[mid] < g) lo = mid + 1; else hi = mid; }
    goff[g] = lo;
    if (g == 0) goff[N_GRAPHS] = N_NODES;
}

// ---------------- build B_cat2[l][512][256], gate-interleaved columns ----------------
// j' = ch*4 + gate (gate: 0=r, 1=z, 2=i_n, 3=h_n); maps to old j = gate*128 + ch.
__global__ __launch_bounds__(256) void build_bcat(const unsigned short* __restrict__ Wp,
                                                  const unsigned short* __restrict__ Whh,
                                                  unsigned short* __restrict__ Bcat) {
    int idx = blockIdx.x * 256 + threadIdx.x;   // L*512*256
    if (idx >= N_LAYERS * 512 * 256) return;
    int l = idx >> 17;
    int rem = idx & 131071;
    int jp = rem >> 8;
    int k = rem & 255;
    int gate = jp & 3;
    int ch = jp >> 2;
    int j = gate * 128 + ch;
    unsigned short v = 0;
    if (j < 256) {
        v = (k < 128) ? Wp[((size_t)l * 384 + j) * 128 + k]
                      : Whh[((size_t)l * 384 + j) * 128 + (k - 128)];
    } else if (j < 384) {
        v = (k < 128) ? Wp[((size_t)l * 384 + j) * 128 + k] : (unsigned short)0;
    } else {
        v = (k >= 128) ? Whh[((size_t)l * 384 + (j - 128)) * 128 + (k - 128)] : (unsigned short)0;
    }
    Bcat[idx] = v;
}

// ---------------- CSR build ----------------
__global__ __launch_bounds__(256) void hist_dst(const int* __restrict__ dst,
                                                int* __restrict__ deg) {
    int e = blockIdx.x * 256 + threadIdx.x;
    if (e < N_EDGES) atomicAdd(&deg[dst[e]], 1);
}

__global__ __launch_bounds__(256) void block_sum(const int* __restrict__ deg,
                                                 int* __restrict__ bsum) {
    __shared__ int s[256];
    int t = threadIdx.x;
    int i = blockIdx.x * 256 + t;
    s[t] = (i < N_NODES) ? deg[i] : 0;
    __syncthreads();
    for (int o = 128; o > 0; o >>= 1) {
        if (t < o) s[t] += s[t + o];
        __syncthreads();
    }
    if (t == 0) bsum[blockIdx.x] = s[0];
}

__global__ __launch_bounds__(256) void scan_partials(const int* __restrict__ bsum,
                                                     int* __restrict__ boff,
                                                     int* __restrict__ row_ptr) {
    __shared__ int s[256];
    int t = threadIdx.x;
    int v = (t < NBLK_SCAN) ? bsum[t] : 0;
    s[t] = v;
    __syncthreads();
    for (int o = 1; o < 256; o <<= 1) {
        int x = (t >= o) ? s[t - o] : 0;
        __syncthreads();
        s[t] += x;
        __syncthreads();
    }
    if (t < NBLK_SCAN) boff[t] = s[t] - v;   // exclusive
    if (t == 255) row_ptr[N_NODES] = s[255];
}

__global__ __launch_bounds__(256) void scan_final(const int* __restrict__ deg,
                                                  const int* __restrict__ boff,
                                                  int* __restrict__ row_ptr,
                                                  int* __restrict__ pos) {
    __shared__ int s[256];
    int t = threadIdx.x;
    int i = blockIdx.x * 256 + t;
    int v = (i < N_NODES) ? deg[i] : 0;
    s[t] = v;
    __syncthreads();
    for (int o = 1; o < 256; o <<= 1) {
        int x = (t >= o) ? s[t - o] : 0;
        __syncthreads();
        s[t] += x;
        __syncthreads();
    }
    int excl = s[t] - v + boff[blockIdx.x];
    if (i < N_NODES) {
        row_ptr[i] = excl;
        pos[i] = excl;
    }
}

__global__ __launch_bounds__(256) void fill_csr(const int* __restrict__ src,
                                                const int* __restrict__ dst,
                                                int* __restrict__ pos,
                                                int* __restrict__ csr_src) {
    int e = blockIdx.x * 256 + threadIdx.x;
    if (e >= N_EDGES) return;
    int p = atomicAdd(&pos[dst[e]], 1);
    csr_src[p] = src[e];
}

// ---------------- gather: cat[n, 0:128] = sum_{e:dst=n} cat[src[e], 128:256] ----------------
__global__ __launch_bounds__(256) void gather_agg(unsigned short* __restrict__ cat,
                                                  const int* __restrict__ row_ptr,
                                                  const int* __restrict__ csr_src) {
    int t = threadIdx.x;
    int node = blockIdx.x * 16 + (t >> 4);
    int c8 = (t & 15) * 8;
    if (node >= N_NODES) return;
    int b = row_ptr[node];
    int e2 = row_ptr[node + 1];
    float acc0[8] = {}, acc1[8] = {}, acc2[8] = {}, acc3[8] = {};
    int e = b;
    for (; e + 4 <= e2; e += 4) {
        int s0 = csr_src[e];
        int s1 = csr_src[e + 1];
        int s2 = csr_src[e + 2];
        int s3 = csr_src[e + 3];
        bf16x8 v0 = *(const bf16x8*)(cat + (size_t)s0 * 256 + 128 + c8);
        bf16x8 v1 = *(const bf16x8*)(cat + (size_t)s1 * 256 + 128 + c8);
        bf16x8 v2 = *(const bf16x8*)(cat + (size_t)s2 * 256 + 128 + c8);
        bf16x8 v3 = *(const bf16x8*)(cat + (size_t)s3 * 256 + 128 + c8);
        #pragma unroll
        for (int j = 0; j < 8; ++j) {
            acc0[j] += bf2f((unsigned short)v0[j]);
            acc1[j] += bf2f((unsigned short)v1[j]);
            acc2[j] += bf2f((unsigned short)v2[j]);
            acc3[j] += bf2f((unsigned short)v3[j]);
        }
    }
    for (; e < e2; ++e) {
        int s0 = csr_src[e];
        bf16x8 v0 = *(const bf16x8*)(cat + (size_t)s0 * 256 + 128 + c8);
        #pragma unroll
        for (int j = 0; j < 8; ++j) acc0[j] += bf2f((unsigned short)v0[j]);
    }
    bf16x8 ov;
    #pragma unroll
    for (int j = 0; j < 8; ++j) ov[j] = (short)f2bf((acc0[j] + acc1[j]) + (acc2[j] + acc3[j]));
    *(bf16x8*)(cat + (size_t)node * 256 + c8) = ov;
}

// ---------------- generic bf16 MFMA GEMM (used for the tiny W' precompute) ----------------
__global__ __launch_bounds__(256) void gemm_bf16(const unsigned short* __restrict__ A, int Ap,
                                                 const unsigned short* __restrict__ W, int Wp,
                                                 unsigned short* __restrict__ out, int Op,
                                                 int M, int Kd,
                                                 size_t lsA, size_t lsW, size_t lsO) {
    A += (size_t)blockIdx.z * lsA;
    W += (size_t)blockIdx.z * lsW;
    out += (size_t)blockIdx.z * lsO;

    __shared__ unsigned short As[128 * 72];
    __shared__ unsigned short Bs[128 * 72];

    const int tid = threadIdx.x;
    const int i0 = blockIdx.x * 128;
    const int j0 = blockIdx.y * 128;

    const int wave = tid >> 6;
    const int lane = tid & 63;
    const int m16 = lane & 15;
    const int quad = lane >> 4;
    const int mr = (wave & 1) * 64;
    const int nc = (wave >> 1) * 64;

    f32x4 acc[4][4];
    #pragma unroll
    for (int a = 0; a < 4; ++a)
        #pragma unroll
        for (int b = 0; b < 4; ++b)
            acc[a][b] = (f32x4){0.f, 0.f, 0.f, 0.f};

    const int r0 = tid >> 3;
    const int kk = (tid & 7) * 8;

    for (int kc = 0; kc < Kd; kc += 64) {
        if (kc) __syncthreads();
        #pragma unroll
        for (int it = 0; it < 4; ++it) {
            int r = r0 + it * 32;
            int gi_ = i0 + r;
            bf16x8 av = {0, 0, 0, 0, 0, 0, 0, 0};
            if (gi_ < M) av = *(const bf16x8*)(A + (size_t)gi_ * Ap + kc + kk);
            *(bf16x8*)&As[r * 72 + kk] = av;
            *(bf16x8*)&Bs[r * 72 + kk] = *(const bf16x8*)(W + (size_t)(j0 + r) * Wp + kc + kk);
        }
        __syncthreads();

        #pragma unroll
        for (int ks = 0; ks < 64; ks += 32) {
            bf16x8 af[4], bf_[4];
            #pragma unroll
            for (int rt = 0; rt < 4; ++rt)
                af[rt] = *(const bf16x8*)&As[(mr + rt * 16 + m16) * 72 + ks + quad * 8];
            #pragma unroll
            for (int ct = 0; ct < 4; ++ct)
                bf_[ct] = *(const bf16x8*)&Bs[(nc + ct * 16 + m16) * 72 + ks + quad * 8];
            #pragma unroll
            for (int rt = 0; rt < 4; ++rt)
                #pragma unroll
                for (int ct = 0; ct < 4; ++ct)
                    acc[rt][ct] = __builtin_amdgcn_mfma_f32_16x16x32_bf16(
                        af[rt], bf_[ct], acc[rt][ct], 0, 0, 0);
        }
    }

    #pragma unroll
    for (int rt = 0; rt < 4; ++rt) {
        #pragma unroll
        for (int r4 = 0; r4 < 4; ++r4) {
            int i = i0 + mr + rt * 16 + quad * 4 + r4;
            if (i >= M) continue;
            #pragma unroll
            for (int ct = 0; ct < 4; ++ct) {
                int j = j0 + nc + ct * 16 + m16;
                out[(size_t)i * Op + j] = f2bf(acc[rt][ct][r4]);
            }
        }
    }
}

// ---------------- fused GEMM + GRU gates: async LDS staging + XOR-swizzled layout ----------------
__global__ __launch_bounds__(256) void gemm_gru(const unsigned short* __restrict__ catR,
                                                unsigned short* __restrict__ catW,
                                                const unsigned short* __restrict__ W,
                                                const float* __restrict__ bc) {
    __shared__ unsigned short As[128 * 64];   // weight tile; reused as Lo in epilogue
    __shared__ unsigned short Bs[128 * 64];   // node tile
    unsigned short* Lo = As;                  // [128][40] bf16 out staging (10240 B)

    const int tid = threadIdx.x;
    const int i0 = blockIdx.x * 128;   // node base
    const int j0 = blockIdx.y * 128;   // j' base
    const int ch_base = blockIdx.y * 32;

    const int wave = tid >> 6;
    const int lane = tid & 63;
    const int m16 = lane & 15;
    const int quad = lane >> 4;
    const int mr = (wave & 1) * 64;    // j' sub-tile
    const int nc = (wave >> 1) * 64;   // node sub-tile
    const int chw = ch_base + (wave & 1) * 16;

    const int rb = lane >> 3;                       // 0..7
    const int cswz = (((lane & 7) ^ rb) * 8);       // ushort offset of fetched chunk

    const int h_chunk = (ch_base & 64) ? 192 : 128;

    f32x4 acc[4][4];
    #pragma unroll
    for (int a = 0; a < 4; ++a)
        #pragma unroll
        for (int b = 0; b < 4; ++b)
            acc[a][b] = (f32x4){0.f, 0.f, 0.f, 0.f};

    float hold[4][4];

    for (int kc = 0; kc < 256; kc += 64) {
        if (kc) __syncthreads();
        #pragma unroll
        for (int it = 0; it < 4; ++it) {
            int rowbase = it * 32 + wave * 8;          // wave-uniform
            int row = rowbase + rb;
            dma16(W + (size_t)(j0 + row) * 256 + kc + cswz, &As[rowbase * 64]);
            int gn = i0 + row;
            if (gn < N_NODES)
                dma16(catR + (size_t)gn * 256 + kc + cswz, &Bs[rowbase * 64]);
        }
        __syncthreads();

        if (kc == h_chunk) {
            #pragma unroll
            for (int rt = 0; rt < 4; ++rt) {
                int ch = chw + rt * 4 + quad;
                int off = 128 + ch - h_chunk;   // 0..63 ushort within chunk
                #pragma unroll
                for (int ct = 0; ct < 4; ++ct) {
                    int row = nc + ct * 16 + m16;
                    int idx = row * 64 + (((off >> 3) ^ (row & 7)) * 8) + (off & 7);
                    hold[rt][ct] = bf2f(Bs[idx]);
                }
            }
        }

        #pragma unroll
        for (int ks = 0; ks < 64; ks += 32) {
            const int cbase = (ks >> 3) + quad;   // logical 16B chunk index
            bf16x8 af[4], bf_[4];
            #pragma unroll
            for (int rt = 0; rt < 4; ++rt) {
                int row = mr + rt * 16 + m16;
                af[rt] = *(const bf16x8*)&As[row * 64 + ((cbase ^ (row & 7)) * 8)];
            }
            #pragma unroll
            for (int ct = 0; ct < 4; ++ct) {
                int row = nc + ct * 16 + m16;
                bf_[ct] = *(const bf16x8*)&Bs[row * 64 + ((cbase ^ (row & 7)) * 8)];
            }
            #pragma unroll
            for (int rt = 0; rt < 4; ++rt)
                #pragma unroll
                for (int ct = 0; ct < 4; ++ct)
                    acc[rt][ct] = __builtin_amdgcn_mfma_f32_16x16x32_bf16(
                        af[rt], bf_[ct], acc[rt][ct], 0, 0, 0);
        }
    }

    // epilogue: gates straight from accumulators -> Lo (LDS) -> coalesced stores
    __syncthreads();
    #pragma unroll
    for (int rt = 0; rt < 4; ++rt) {
        int ch = chw + rt * 4 + quad;
        float br  = bc[ch];
        float bz  = bc[128 + ch];
        float bni = bc[256 + ch];
        float bnh = bc[384 + ch];
        int chl = ch - ch_base;   // 0..31
        #pragma unroll
        for (int ct = 0; ct < 4; ++ct) {
            int rloc = nc + ct * 16 + m16;
            float r = 1.f / (1.f + __expf(-(acc[rt][ct][0] + br)));
            float z = 1.f / (1.f + __expf(-(acc[rt][ct][1] + bz)));
            float a = acc[rt][ct][2] + bni + r * (acc[rt][ct][3] + bnh);
            a = fminf(fmaxf(a, -20.f), 20.f);
            float t2 = __expf(2.f * a);
            float n = (t2 - 1.f) / (t2 + 1.f);
            float o = (1.f - z) * n + z * hold[rt][ct];
            o = o > 0.f ? o : 0.f;
            Lo[rloc * 40 + chl] = f2bf(o);
        }
    }
    __syncthreads();
    #pragma unroll
    for (int it = 0; it < 2; ++it) {
        int unit = it * 256 + tid;      // 0..511 = 128 rows x 4 segs
        int row = unit >> 2;
        int seg = (unit & 3) * 8;
        int node = i0 + row;
        if (node < N_NODES)
            *(bf16x8*)(catW + (size_t)node * 256 + 128 + ch_base + seg) =
                *(const bf16x8*)&Lo[row * 40 + seg];
    }
}

// ---------------- mean pool: 16 row-groups x 16 ch-groups, bf16x8 loads + LDS tree ----------------
__global__ __launch_bounds__(256) void pool_sorted(const unsigned short* __restrict__ cat,
                                                   const int* __restrict__ goff,
                                                   float* __restrict__ hg) {
    __shared__ float red[16][16][8];   // [rowgrp][chgrp][8] = 8 KB
    int g = blockIdx.x;
    int start = goff[g];
    int end = goff[g + 1];
    int rg = threadIdx.x >> 4;    // 0..15
    int cg = threadIdx.x & 15;    // 0..15
    float acc[8] = {};
    for (int i = start + rg; i < end; i += 16) {
        bf16x8 v = *(const bf16x8*)(cat + (size_t)i * 256 + 128 + cg * 8);
        #pragma unroll
        for (int j = 0; j < 8; ++j) acc[j] += bf2f((unsigned short)v[j]);
    }
    #pragma unroll
    for (int j = 0; j < 8; ++j) red[rg][cg][j] = acc[j];
    __syncthreads();
    for (int o = 8; o > 0; o >>= 1) {
        if (rg < o) {
            #pragma unroll
            for (int j = 0; j < 8; ++j) red[rg][cg][j] += red[rg + o][cg][j];
        }
        __syncthreads();
    }
    if (rg == 0) {
        float cnt = fmaxf((float)(end - start), 1.f);
        #pragma unroll
        for (int j = 0; j < 8; ++j)
            hg[(size_t)g * D + cg * 8 + j] = red[0][cg][j] / cnt;
    }
}

// ---------------- fused fc1(elu) + fc2 per graph ----------------
__global__ __launch_bounds__(128) void fc12(const float* __restrict__ hg,
                                            const float* __restrict__ w1,
                                            const float* __restrict__ b1,
                                            const float* __restrict__ w2,
                                            const float* __restrict__ b2,
                                            float* __restrict__ logits) {
    __shared__ float row[128];
    __shared__ float zrow[128];
    int g = blockIdx.x;
    int j = threadIdx.x;
    row[j] = hg[(size_t)g * 128 + j];
    __syncthreads();
    float acc = b1[j];
    const float* wr = w1 + (size_t)j * 128;
    #pragma unroll 4
    for (int k = 0; k < 128; ++k) acc += row[k] * wr[k];
    zrow[j] = acc > 0.f ? acc : (expf(acc) - 1.f);
    __syncthreads();
    if (j < N_CLASSES) {
        float a2 = b2[j];
        const float* w2r = w2 + (size_t)j * 128;
        #pragma unroll 4
        for (int k = 0; k < 128; ++k) a2 += zrow[k] * w2r[k];
        logits[(size_t)g * N_CLASSES + j] = a2;
    }
}

// ---------------- log_softmax over axis 0 ----------------
__global__ __launch_bounds__(512) void logsoftmax_axis0(const float* __restrict__ logits,
                                                        float* __restrict__ out) {
    __shared__ float red[512];
    int c = blockIdx.x;
    int g = threadIdx.x;
    float x = logits[(size_t)g * N_CLASSES + c];
    red[g] = x;
    __syncthreads();
    for (int s = 256; s > 0; s >>= 1) {
        if (g < s) red[g] = fmaxf(red[g], red[g + s]);
        __syncthreads();
    }
    float mx = red[0];
    __syncthreads();
    red[g] = expf(x - mx);
    __syncthreads();
    for (int s = 256; s > 0; s >>= 1) {
        if (g < s) red[g] += red[g + s];
        __syncthreads();
    }
    float lse = mx + logf(red[0]);
    out[(size_t)g * N_CLASSES + c] = x - lse;
}

// ---------------- launch ----------------
extern "C" void kernel_launch(void* const* d_in, const int* in_sizes, int n_in,
                              void* d_out, int out_size, void* d_ws, size_t ws_size,
                              hipStream_t stream) {
    const float* h_in   = (const float*)d_in[0];
    const int*   eidx   = (const int*)d_in[1];
    const int*   batch  = (const int*)d_in[3];
    const float* Ws     = (const float*)d_in[4];
    const float* W_ih   = (const float*)d_in[5];
    const float* W_hh   = (const float*)d_in[6];
    const float* b_ih   = (const float*)d_in[7];
    const float* b_hh   = (const float*)d_in[8];
    const float* fc1_w  = (const float*)d_in[9];
    const float* fc1_b  = (const float*)d_in[10];
    const float* fc2_w  = (const float*)d_in[11];
    const float* fc2_b  = (const float*)d_in[12];
    float* out = (float*)d_out;

    char* ws = (char*)d_ws;
    size_t off = 0;
    auto alloc = [&](size_t bytes) {
        void* p = ws + off;
        off += (bytes + 255) & ~(size_t)255;
        return p;
    };
    unsigned short* catA = (unsigned short*)alloc((size_t)N_NODES * 256 * 2);  // [agg | h] bf16
    unsigned short* catB = (unsigned short*)alloc((size_t)N_NODES * 256 * 2);
    unsigned short* Ws_bf  = (unsigned short*)alloc((size_t)N_LAYERS * D * D * 2);
    unsigned short* Wih_bf = (unsigned short*)alloc((size_t)N_LAYERS * 3 * D * D * 2);
    unsigned short* Whh_bf = (unsigned short*)alloc((size_t)N_LAYERS * 3 * D * D * 2);
    unsigned short* Wp_bf  = (unsigned short*)alloc((size_t)N_LAYERS * 3 * D * D * 2);  // Wih @ Ws^T
    unsigned short* Bcat   = (unsigned short*)alloc((size_t)N_LAYERS * 512 * 256 * 2);
    float* bc   = (float*)alloc((size_t)N_LAYERS * 512 * 4);
    float* hg   = (float*)alloc((size_t)N_GRAPHS * D * 4);
    float* lgts = (float*)alloc((size_t)N_GRAPHS * N_CLASSES * 4);
    int* deg     = (int*)alloc((size_t)N_NODES * 4);
    int* row_ptr = (int*)alloc((size_t)(N_NODES + 1) * 4);
    int* pos     = (int*)alloc((size_t)N_NODES * 4);
    int* csr_src = (int*)alloc((size_t)N_EDGES * 4);
    int* bsum    = (int*)alloc((size_t)NBLK_SCAN * 4);
    int* boff    = (int*)alloc((size_t)NBLK_SCAN * 4);
    int* goff    = (int*)alloc((size_t)(N_GRAPHS + 1) * 4);

    const int* src = eidx;
    const int* dst = eidx + N_EDGES;

    init_all<<<(N_NODES * D + 255) / 256, 256, 0, stream>>>(
        h_in, Ws, W_ih, W_hh, b_ih, b_hh, catA, Ws_bf, Wih_bf, Whh_bf, bc);
    graph_bounds<<<1, 512, 0, stream>>>(batch, goff);

    // W'_l = Wih_l @ Ws_l^T, batched over layers via grid.z
    gemm_bf16<<<dim3(3, 1, N_LAYERS), 256, 0, stream>>>(
        Wih_bf, 128, Ws_bf, 128, Wp_bf, 128, 384, 128,
        (size_t)384 * 128, (size_t)128 * 128, (size_t)384 * 128);
    build_bcat<<<(N_LAYERS * 512 * 256 + 255) / 256, 256, 0, stream>>>(Wp_bf, Whh_bf, Bcat);

    // CSR build (edges static) — distributed scan
    fill_zero4<<<(N_NODES / 4 + 255) / 256, 256, 0, stream>>>((float4*)deg, N_NODES / 4);
    hist_dst<<<(N_EDGES + 255) / 256, 256, 0, stream>>>(dst, deg);
    block_sum<<<NBLK_SCAN, 256, 0, stream>>>(deg, bsum);
    scan_partials<<<1, 256, 0, stream>>>(bsum, boff, row_ptr);
    scan_final<<<NBLK_SCAN, 256, 0, stream>>>(deg, boff, row_ptr, pos);
    fill_csr<<<(N_EDGES + 255) / 256, 256, 0, stream>>>(src, dst, pos, csr_src);

    const int mtiles = (N_NODES + 127) / 128;   // 391
    for (int l = 0; l < N_LAYERS; ++l) {
        unsigned short* catR = (l & 1) ? catB : catA;
        unsigned short* catW = (l & 1) ? catA : catB;
        // catR[:,0:128] = gather of catR[:,128:256]  (agg of h)
        gather_agg<<<(N_NODES + 15) / 16, 256, 0, stream>>>(catR, row_ptr, csr_src);
        // fused: gates(catR @ Bcat2_l^T) -> catW[:,128:256] (new h, bf16)
        gemm_gru<<<dim3(mtiles, 4), 256, 0, stream>>>(
            catR, catW, Bcat + (size_t)l * 512 * 256, bc + (size_t)l * 512);
    }

    // after 4 layers (even), final h lives in catA[:,128:256]
    pool_sorted<<<N_GRAPHS, 256, 0, stream>>>(catA, goff, hg);
    fc12<<<N_GRAPHS, 128, 0, stream>>>(hg, fc1_w, fc1_b, fc2_w, fc2_b, lgts);
    logsoftmax_axis0<<<N_CLASSES, 512, 0, stream>>>(lgts, out);
}

// Round 12
// 421.159 us; speedup vs baseline: 1.2555x; 1.0239x over previous
//
#include <hip/hip_runtime.h>
#include <math.h>

#define N_NODES 50000
#define N_EDGES 600000
#define D 128
#define N_GRAPHS 512
#define N_CLASSES 10
#define N_LAYERS 4
#define NBLK_SCAN 196   // ceil(50000/256)

typedef __attribute__((ext_vector_type(8))) short bf16x8;
typedef __attribute__((ext_vector_type(4))) float f32x4;

__device__ inline unsigned short f2bf(float f) {
    union { float f; unsigned int u; } v; v.f = f;
    unsigned int r = (v.u + 0x7fffu + ((v.u >> 16) & 1u)) >> 16;
    return (unsigned short)r;
}
__device__ inline float bf2f(unsigned short u) {
    union { unsigned int u; float f; } v; v.u = ((unsigned int)u) << 16;
    return v.f;
}

// async global -> LDS, 16B per lane; LDS dest = wave-uniform base + lane*16
typedef __attribute__((address_space(1))) const void GV;
typedef __attribute__((address_space(3))) void LV;
__device__ __forceinline__ void dma16(const void* g, void* l) {
    __builtin_amdgcn_global_load_lds((GV*)g, (LV*)l, 16, 0, 0);
}

// ---------------- fused init: h bf16 mirror + weights bf16 + bias + graph bounds + deg=0 ----------------
// bc layout [L][512]: j<128: bih_r+bhh_r ; 128..256: bih_z+bhh_z ; 256..384: bih_n ; 384..512: bhh_n
__global__ __launch_bounds__(256) void init_all(const float* __restrict__ h_in,
                                                const float* __restrict__ Ws,
                                                const float* __restrict__ Wih,
                                                const float* __restrict__ Whh,
                                                const float* __restrict__ bih,
                                                const float* __restrict__ bhh,
                                                const int* __restrict__ batch,
                                                unsigned short* __restrict__ catA,
                                                unsigned short* __restrict__ Ws_bf,
                                                unsigned short* __restrict__ Wih_bf,
                                                unsigned short* __restrict__ Whh_bf,
                                                float* __restrict__ bc,
                                                int* __restrict__ goff,
                                                int* __restrict__ deg) {
    int idx = blockIdx.x * 256 + threadIdx.x;
    if (idx < N_NODES * D) {
        int i = idx >> 7;
        int c = idx & 127;
        catA[(size_t)i * 256 + 128 + c] = f2bf(h_in[idx]);
    }
    if (idx < N_LAYERS * D * D) Ws_bf[idx] = f2bf(Ws[idx]);
    if (idx < N_LAYERS * 3 * D * D) {
        Wih_bf[idx] = f2bf(Wih[idx]);
        Whh_bf[idx] = f2bf(Whh[idx]);
    }
    if (idx < N_LAYERS * 512) {
        int l = idx >> 9;
        int j = idx & 511;
        const float* bi = bih + (size_t)l * 384;
        const float* bh = bhh + (size_t)l * 384;
        float v;
        if (j < 256) v = bi[j] + bh[j];
        else if (j < 384) v = bi[j];
        else v = bh[j - 128];
        bc[idx] = v;
    }
    if (idx < N_NODES) deg[idx] = 0;
    if (idx < N_GRAPHS) {
        int g = idx;
        int lo = 0, hi = N_NODES;
        while (lo < hi) { int mid = (lo + hi) >> 1; if (batch[mid] < g) lo = mid + 1; else hi = mid; }
        goff[g] = lo;
        if (g == 0) goff[N_GRAPHS] = N_NODES;
    }
}

// ---------------- build B_cat2[l][512][256], gate-interleaved columns ----------------
// j' = ch*4 + gate (gate: 0=r, 1=z, 2=i_n, 3=h_n); maps to old j = gate*128 + ch.
__global__ __launch_bounds__(256) void build_bcat(const unsigned short* __restrict__ Wp,
                                                  const unsigned short* __restrict__ Whh,
                                                  unsigned short* __restrict__ Bcat) {
    int idx = blockIdx.x * 256 + threadIdx.x;   // L*512*256
    if (idx >= N_LAYERS * 512 * 256) return;
    int l = idx >> 17;
    int rem = idx & 131071;
    int jp = rem >> 8;
    int k = rem & 255;
    int gate = jp & 3;
    int ch = jp >> 2;
    int j = gate * 128 + ch;
    unsigned short v = 0;
    if (j < 256) {
        v = (k < 128) ? Wp[((size_t)l * 384 + j) * 128 + k]
                      : Whh[((size_t)l * 384 + j) * 128 + (k - 128)];
    } else if (j < 384) {
        v = (k < 128) ? Wp[((size_t)l * 384 + j) * 128 + k] : (unsigned short)0;
    } else {
        v = (k >= 128) ? Whh[((size_t)l * 384 + (j - 128)) * 128 + (k - 128)] : (unsigned short)0;
    }
    Bcat[idx] = v;
}

// ---------------- CSR build ----------------
__global__ __launch_bounds__(256) void hist_dst(const int* __restrict__ dst,
                                                int* __restrict__ deg) {
    int e = blockIdx.x * 256 + threadIdx.x;
    if (e < N_EDGES) atomicAdd(&deg[dst[e]], 1);
}

__global__ __launch_bounds__(256) void block_sum(const int* __restrict__ deg,
                                                 int* __restrict__ bsum) {
    __shared__ int s[256];
    int t = threadIdx.x;
    int i = blockIdx.x * 256 + t;
    s[t] = (i < N_NODES) ? deg[i] : 0;
    __syncthreads();
    for (int o = 128; o > 0; o >>= 1) {
        if (t < o) s[t] += s[t + o];
        __syncthreads();
    }
    if (t == 0) bsum[blockIdx.x] = s[0];
}

__global__ __launch_bounds__(256) void scan_partials(const int* __restrict__ bsum,
                                                     int* __restrict__ boff,
                                                     int* __restrict__ row_ptr) {
    __shared__ int s[256];
    int t = threadIdx.x;
    int v = (t < NBLK_SCAN) ? bsum[t] : 0;
    s[t] = v;
    __syncthreads();
    for (int o = 1; o < 256; o <<= 1) {
        int x = (t >= o) ? s[t - o] : 0;
        __syncthreads();
        s[t] += x;
        __syncthreads();
    }
    if (t < NBLK_SCAN) boff[t] = s[t] - v;   // exclusive
    if (t == 255) row_ptr[N_NODES] = s[255];
}

__global__ __launch_bounds__(256) void scan_final(const int* __restrict__ deg,
                                                  const int* __restrict__ boff,
                                                  int* __restrict__ row_ptr,
                                                  int* __restrict__ pos) {
    __shared__ int s[256];
    int t = threadIdx.x;
    int i = blockIdx.x * 256 + t;
    int v = (i < N_NODES) ? deg[i] : 0;
    s[t] = v;
    __syncthreads();
    for (int o = 1; o < 256; o <<= 1) {
        int x = (t >= o) ? s[t - o] : 0;
        __syncthreads();
        s[t] += x;
        __syncthreads();
    }
    int excl = s[t] - v + boff[blockIdx.x];
    if (i < N_NODES) {
        row_ptr[i] = excl;
        pos[i] = excl;
    }
}

__global__ __launch_bounds__(256) void fill_csr(const int* __restrict__ src,
                                                const int* __restrict__ dst,
                                                int* __restrict__ pos,
                                                int* __restrict__ csr_src) {
    int e = blockIdx.x * 256 + threadIdx.x;
    if (e >= N_EDGES) return;
    int p = atomicAdd(&pos[dst[e]], 1);
    csr_src[p] = src[e];
}

// ---------------- gather: one wave per node, 4-way edge-parallel + shuffle reduce ----------------
// cat[n, 0:128] = sum_{e: dst=n} cat[src[e], 128:256]
// lane = eg*16 + cg: eg processes edges e = b+eg, b+eg+4, ...; cg picks the 16B chunk.
__global__ __launch_bounds__(256) void gather_agg(unsigned short* __restrict__ cat,
                                                  const int* __restrict__ row_ptr,
                                                  const int* __restrict__ csr_src) {
    int t = threadIdx.x;
    int node = blockIdx.x * 4 + (t >> 6);
    int lane = t & 63;
    int eg = lane >> 4;          // 0..3 edge-group
    int c8 = (lane & 15) * 8;    // channel chunk
    if (node >= N_NODES) return;
    int b = row_ptr[node];
    int e2 = row_ptr[node + 1];
    float acc0[8] = {}, acc1[8] = {};
    int e = b + eg;
    for (; e + 4 < e2; e += 8) {
        int s0 = csr_src[e];
        int s1 = csr_src[e + 4];
        bf16x8 v0 = *(const bf16x8*)(cat + (size_t)s0 * 256 + 128 + c8);
        bf16x8 v1 = *(const bf16x8*)(cat + (size_t)s1 * 256 + 128 + c8);
        #pragma unroll
        for (int j = 0; j < 8; ++j) {
            acc0[j] += bf2f((unsigned short)v0[j]);
            acc1[j] += bf2f((unsigned short)v1[j]);
        }
    }
    if (e < e2) {
        int s0 = csr_src[e];
        bf16x8 v0 = *(const bf16x8*)(cat + (size_t)s0 * 256 + 128 + c8);
        #pragma unroll
        for (int j = 0; j < 8; ++j) acc0[j] += bf2f((unsigned short)v0[j]);
    }
    float a[8];
    #pragma unroll
    for (int j = 0; j < 8; ++j) a[j] = acc0[j] + acc1[j];
    // reduce over the 4 edge-groups (lanes 16 and 32 apart)
    #pragma unroll
    for (int j = 0; j < 8; ++j) {
        a[j] += __shfl_xor(a[j], 16, 64);
        a[j] += __shfl_xor(a[j], 32, 64);
    }
    if (eg == 0) {
        bf16x8 ov;
        #pragma unroll
        for (int j = 0; j < 8; ++j) ov[j] = (short)f2bf(a[j]);
        *(bf16x8*)(cat + (size_t)node * 256 + c8) = ov;
    }
}

// ---------------- generic bf16 MFMA GEMM (used for the tiny W' precompute) ----------------
__global__ __launch_bounds__(256) void gemm_bf16(const unsigned short* __restrict__ A, int Ap,
                                                 const unsigned short* __restrict__ W, int Wp,
                                                 unsigned short* __restrict__ out, int Op,
                                                 int M, int Kd,
                                                 size_t lsA, size_t lsW, size_t lsO) {
    A += (size_t)blockIdx.z * lsA;
    W += (size_t)blockIdx.z * lsW;
    out += (size_t)blockIdx.z * lsO;

    __shared__ unsigned short As[128 * 72];
    __shared__ unsigned short Bs[128 * 72];

    const int tid = threadIdx.x;
    const int i0 = blockIdx.x * 128;
    const int j0 = blockIdx.y * 128;

    const int wave = tid >> 6;
    const int lane = tid & 63;
    const int m16 = lane & 15;
    const int quad = lane >> 4;
    const int mr = (wave & 1) * 64;
    const int nc = (wave >> 1) * 64;

    f32x4 acc[4][4];
    #pragma unroll
    for (int a = 0; a < 4; ++a)
        #pragma unroll
        for (int b = 0; b < 4; ++b)
            acc[a][b] = (f32x4){0.f, 0.f, 0.f, 0.f};

    const int r0 = tid >> 3;
    const int kk = (tid & 7) * 8;

    for (int kc = 0; kc < Kd; kc += 64) {
        if (kc) __syncthreads();
        #pragma unroll
        for (int it = 0; it < 4; ++it) {
            int r = r0 + it * 32;
            int gi_ = i0 + r;
            bf16x8 av = {0, 0, 0, 0, 0, 0, 0, 0};
            if (gi_ < M) av = *(const bf16x8*)(A + (size_t)gi_ * Ap + kc + kk);
            *(bf16x8*)&As[r * 72 + kk] = av;
            *(bf16x8*)&Bs[r * 72 + kk] = *(const bf16x8*)(W + (size_t)(j0 + r) * Wp + kc + kk);
        }
        __syncthreads();

        #pragma unroll
        for (int ks = 0; ks < 64; ks += 32) {
            bf16x8 af[4], bf_[4];
            #pragma unroll
            for (int rt = 0; rt < 4; ++rt)
                af[rt] = *(const bf16x8*)&As[(mr + rt * 16 + m16) * 72 + ks + quad * 8];
            #pragma unroll
            for (int ct = 0; ct < 4; ++ct)
                bf_[ct] = *(const bf16x8*)&Bs[(nc + ct * 16 + m16) * 72 + ks + quad * 8];
            #pragma unroll
            for (int rt = 0; rt < 4; ++rt)
                #pragma unroll
                for (int ct = 0; ct < 4; ++ct)
                    acc[rt][ct] = __builtin_amdgcn_mfma_f32_16x16x32_bf16(
                        af[rt], bf_[ct], acc[rt][ct], 0, 0, 0);
        }
    }

    #pragma unroll
    for (int rt = 0; rt < 4; ++rt) {
        #pragma unroll
        for (int r4 = 0; r4 < 4; ++r4) {
            int i = i0 + mr + rt * 16 + quad * 4 + r4;
            if (i >= M) continue;
            #pragma unroll
            for (int ct = 0; ct < 4; ++ct) {
                int j = j0 + nc + ct * 16 + m16;
                out[(size_t)i * Op + j] = f2bf(acc[rt][ct][r4]);
            }
        }
    }
}

// ---------------- fused GEMM + GRU gates: async LDS staging + XOR-swizzled layout ----------------
__global__ __launch_bounds__(256) void gemm_gru(const unsigned short* __restrict__ catR,
                                                unsigned short* __restrict__ catW,
                                                const unsigned short* __restrict__ W,
                                                const float* __restrict__ bc) {
    __shared__ unsigned short As[128 * 64];   // weight tile; reused as Lo in epilogue
    __shared__ unsigned short Bs[128 * 64];   // node tile
    unsigned short* Lo = As;                  // [128][40] bf16 out staging (10240 B)

    const int tid = threadIdx.x;
    const int i0 = blockIdx.x * 128;   // node base
    const int j0 = blockIdx.y * 128;   // j' base
    const int ch_base = blockIdx.y * 32;

    const int wave = tid >> 6;
    const int lane = tid & 63;
    const int m16 = lane & 15;
    const int quad = lane >> 4;
    const int mr = (wave & 1) * 64;    // j' sub-tile
    const int nc = (wave >> 1) * 64;   // node sub-tile
    const int chw = ch_base + (wave & 1) * 16;

    const int rb = lane >> 3;                       // 0..7
    const int cswz = (((lane & 7) ^ rb) * 8);       // ushort offset of fetched chunk

    const int h_chunk = (ch_base & 64) ? 192 : 128;

    f32x4 acc[4][4];
    #pragma unroll
    for (int a = 0; a < 4; ++a)
        #pragma unroll
        for (int b = 0; b < 4; ++b)
            acc[a][b] = (f32x4){0.f, 0.f, 0.f, 0.f};

    float hold[4][4];

    for (int kc = 0; kc < 256; kc += 64) {
        if (kc) __syncthreads();
        #pragma unroll
        for (int it = 0; it < 4; ++it) {
            int rowbase = it * 32 + wave * 8;          // wave-uniform
            int row = rowbase + rb;
            dma16(W + (size_t)(j0 + row) * 256 + kc + cswz, &As[rowbase * 64]);
            int gn = i0 + row;
            if (gn < N_NODES)
                dma16(catR + (size_t)gn * 256 + kc + cswz, &Bs[rowbase * 64]);
        }
        __syncthreads();

        if (kc == h_chunk) {
            #pragma unroll
            for (int rt = 0; rt < 4; ++rt) {
                int ch = chw + rt * 4 + quad;
                int off = 128 + ch - h_chunk;   // 0..63 ushort within chunk
                #pragma unroll
                for (int ct = 0; ct < 4; ++ct) {
                    int row = nc + ct * 16 + m16;
                    int idx = row * 64 + (((off >> 3) ^ (row & 7)) * 8) + (off & 7);
                    hold[rt][ct] = bf2f(Bs[idx]);
                }
            }
        }

        #pragma unroll
        for (int ks = 0; ks < 64; ks += 32) {
            const int cbase = (ks >> 3) + quad;   // logical 16B chunk index
            bf16x8 af[4], bf_[4];
            #pragma unroll
            for (int rt = 0; rt < 4; ++rt) {
                int row = mr + rt * 16 + m16;
                af[rt] = *(const bf16x8*)&As[row * 64 + ((cbase ^ (row & 7)) * 8)];
            }
            #pragma unroll
            for (int ct = 0; ct < 4; ++ct) {
                int row = nc + ct * 16 + m16;
                bf_[ct] = *(const bf16x8*)&Bs[row * 64 + ((cbase ^ (row & 7)) * 8)];
            }
            #pragma unroll
            for (int rt = 0; rt < 4; ++rt)
                #pragma unroll
                for (int ct = 0; ct < 4; ++ct)
                    acc[rt][ct] = __builtin_amdgcn_mfma_f32_16x16x32_bf16(
                        af[rt], bf_[ct], acc[rt][ct], 0, 0, 0);
        }
    }

    // epilogue: gates straight from accumulators -> Lo (LDS) -> coalesced stores
    __syncthreads();
    #pragma unroll
    for (int rt = 0; rt < 4; ++rt) {
        int ch = chw + rt * 4 + quad;
        float br  = bc[ch];
        float bz  = bc[128 + ch];
        float bni = bc[256 + ch];
        float bnh = bc[384 + ch];
        int chl = ch - ch_base;   // 0..31
        #pragma unroll
        for (int ct = 0; ct < 4; ++ct) {
            int rloc = nc + ct * 16 + m16;
            float r = 1.f / (1.f + __expf(-(acc[rt][ct][0] + br)));
            float z = 1.f / (1.f + __expf(-(acc[rt][ct][1] + bz)));
            float a = acc[rt][ct][2] + bni + r * (acc[rt][ct][3] + bnh);
            a = fminf(fmaxf(a, -20.f), 20.f);
            float t2 = __expf(2.f * a);
            float n = (t2 - 1.f) / (t2 + 1.f);
            float o = (1.f - z) * n + z * hold[rt][ct];
            o = o > 0.f ? o : 0.f;
            Lo[rloc * 40 + chl] = f2bf(o);
        }
    }
    __syncthreads();
    #pragma unroll
    for (int it = 0; it < 2; ++it) {
        int unit = it * 256 + tid;      // 0..511 = 128 rows x 4 segs
        int row = unit >> 2;
        int seg = (unit & 3) * 8;
        int node = i0 + row;
        if (node < N_NODES)
            *(bf16x8*)(catW + (size_t)node * 256 + 128 + ch_base + seg) =
                *(const bf16x8*)&Lo[row * 40 + seg];
    }
}

// ---------------- mean pool: 16 row-groups x 16 ch-groups, bf16x8 loads + LDS tree ----------------
__global__ __launch_bounds__(256) void pool_sorted(const unsigned short* __restrict__ cat,
                                                   const int* __restrict__ goff,
                                                   float* __restrict__ hg) {
    __shared__ float red[16][16][8];   // [rowgrp][chgrp][8] = 8 KB
    int g = blockIdx.x;
    int start = goff[g];
    int end = goff[g + 1];
    int rg = threadIdx.x >> 4;    // 0..15
    int cg = threadIdx.x & 15;    // 0..15
    float acc[8] = {};
    for (int i = start + rg; i < end; i += 16) {
        bf16x8 v = *(const bf16x8*)(cat + (size_t)i * 256 + 128 + cg * 8);
        #pragma unroll
        for (int j = 0; j < 8; ++j) acc[j] += bf2f((unsigned short)v[j]);
    }
    #pragma unroll
    for (int j = 0; j < 8; ++j) red[rg][cg][j] = acc[j];
    __syncthreads();
    for (int o = 8; o > 0; o >>= 1) {
        if (rg < o) {
            #pragma unroll
            for (int j = 0; j < 8; ++j) red[rg][cg][j] += red[rg + o][cg][j];
        }
        __syncthreads();
    }
    if (rg == 0) {
        float cnt = fmaxf((float)(end - start), 1.f);
        #pragma unroll
        for (int j = 0; j < 8; ++j)
            hg[(size_t)g * D + cg * 8 + j] = red[0][cg][j] / cnt;
    }
}

// ---------------- fused fc1(elu) + fc2 per graph ----------------
__global__ __launch_bounds__(128) void fc12(const float* __restrict__ hg,
                                            const float* __restrict__ w1,
                                            const float* __restrict__ b1,
                                            const float* __restrict__ w2,
                                            const float* __restrict__ b2,
                                            float* __restrict__ logits) {
    __shared__ float row[128];
    __shared__ float zrow[128];
    int g = blockIdx.x;
    int j = threadIdx.x;
    row[j] = hg[(size_t)g * 128 + j];
    __syncthreads();
    float acc = b1[j];
    const float* wr = w1 + (size_t)j * 128;
    #pragma unroll 4
    for (int k = 0; k < 128; ++k) acc += row[k] * wr[k];
    zrow[j] = acc > 0.f ? acc : (expf(acc) - 1.f);
    __syncthreads();
    if (j < N_CLASSES) {
        float a2 = b2[j];
        const float* w2r = w2 + (size_t)j * 128;
        #pragma unroll 4
        for (int k = 0; k < 128; ++k) a2 += zrow[k] * w2r[k];
        logits[(size_t)g * N_CLASSES + j] = a2;
    }
}

// ---------------- log_softmax over axis 0 ----------------
__global__ __launch_bounds__(512) void logsoftmax_axis0(const float* __restrict__ logits,
                                                        float* __restrict__ out) {
    __shared__ float red[512];
    int c = blockIdx.x;
    int g = threadIdx.x;
    float x = logits[(size_t)g * N_CLASSES + c];
    red[g] = x;
    __syncthreads();
    for (int s = 256; s > 0; s >>= 1) {
        if (g < s) red[g] = fmaxf(red[g], red[g + s]);
        __syncthreads();
    }
    float mx = red[0];
    __syncthreads();
    red[g] = expf(x - mx);
    __syncthreads();
    for (int s = 256; s > 0; s >>= 1) {
        if (g < s) red[g] += red[g + s];
        __syncthreads();
    }
    float lse = mx + logf(red[0]);
    out[(size_t)g * N_CLASSES + c] = x - lse;
}

// ---------------- launch ----------------
extern "C" void kernel_launch(void* const* d_in, const int* in_sizes, int n_in,
                              void* d_out, int out_size, void* d_ws, size_t ws_size,
                              hipStream_t stream) {
    const float* h_in   = (const float*)d_in[0];
    const int*   eidx   = (const int*)d_in[1];
    const int*   batch  = (const int*)d_in[3];
    const float* Ws     = (const float*)d_in[4];
    const float* W_ih   = (const float*)d_in[5];
    const float* W_hh   = (const float*)d_in[6];
    const float* b_ih   = (const float*)d_in[7];
    const float* b_hh   = (const float*)d_in[8];
    const float* fc1_w  = (const float*)d_in[9];
    const float* fc1_b  = (const float*)d_in[10];
    const float* fc2_w  = (const float*)d_in[11];
    const float* fc2_b  = (const float*)d_in[12];
    float* out = (float*)d_out;

    char* ws = (char*)d_ws;
    size_t off = 0;
    auto alloc = [&](size_t bytes) {
        void* p = ws + off;
        off += (bytes + 255) & ~(size_t)255;
        return p;
    };
    unsigned short* catA = (unsigned short*)alloc((size_t)N_NODES * 256 * 2);  // [agg | h] bf16
    unsigned short* catB = (unsigned short*)alloc((size_t)N_NODES * 256 * 2);
    unsigned short* Ws_bf  = (unsigned short*)alloc((size_t)N_LAYERS * D * D * 2);
    unsigned short* Wih_bf = (unsigned short*)alloc((size_t)N_LAYERS * 3 * D * D * 2);
    unsigned short* Whh_bf = (unsigned short*)alloc((size_t)N_LAYERS * 3 * D * D * 2);
    unsigned short* Wp_bf  = (unsigned short*)alloc((size_t)N_LAYERS * 3 * D * D * 2);  // Wih @ Ws^T
    unsigned short* Bcat   = (unsigned short*)alloc((size_t)N_LAYERS * 512 * 256 * 2);
    float* bc   = (float*)alloc((size_t)N_LAYERS * 512 * 4);
    float* hg   = (float*)alloc((size_t)N_GRAPHS * D * 4);
    float* lgts = (float*)alloc((size_t)N_GRAPHS * N_CLASSES * 4);
    int* deg     = (int*)alloc((size_t)N_NODES * 4);
    int* row_ptr = (int*)alloc((size_t)(N_NODES + 1) * 4);
    int* pos     = (int*)alloc((size_t)N_NODES * 4);
    int* csr_src = (int*)alloc((size_t)N_EDGES * 4);
    int* bsum    = (int*)alloc((size_t)NBLK_SCAN * 4);
    int* boff    = (int*)alloc((size_t)NBLK_SCAN * 4);
    int* goff    = (int*)alloc((size_t)(N_GRAPHS + 1) * 4);

    const int* src = eidx;
    const int* dst = eidx + N_EDGES;

    init_all<<<(N_NODES * D + 255) / 256, 256, 0, stream>>>(
        h_in, Ws, W_ih, W_hh, b_ih, b_hh, batch,
        catA, Ws_bf, Wih_bf, Whh_bf, bc, goff, deg);

    // W'_l = Wih_l @ Ws_l^T, batched over layers via grid.z
    gemm_bf16<<<dim3(3, 1, N_LAYERS), 256, 0, stream>>>(
        Wih_bf, 128, Ws_bf, 128, Wp_bf, 128, 384, 128,
        (size_t)384 * 128, (size_t)128 * 128, (size_t)384 * 128);
    build_bcat<<<(N_LAYERS * 512 * 256 + 255) / 256, 256, 0, stream>>>(Wp_bf, Whh_bf, Bcat);

    // CSR build (edges static) — distributed scan
    hist_dst<<<(N_EDGES + 255) / 256, 256, 0, stream>>>(dst, deg);
    block_sum<<<NBLK_SCAN, 256, 0, stream>>>(deg, bsum);
    scan_partials<<<1, 256, 0, stream>>>(bsum, boff, row_ptr);
    scan_final<<<NBLK_SCAN, 256, 0, stream>>>(deg, boff, row_ptr, pos);
    fill_csr<<<(N_EDGES + 255) / 256, 256, 0, stream>>>(src, dst, pos, csr_src);

    const int mtiles = (N_NODES + 127) / 128;   // 391
    for (int l = 0; l < N_LAYERS; ++l) {
        unsigned short* catR = (l & 1) ? catB : catA;
        unsigned short* catW = (l & 1) ? catA : catB;
        // catR[:,0:128] = gather of catR[:,128:256]  (agg of h)
        gather_agg<<<(N_NODES + 3) / 4, 256, 0, stream>>>(catR, row_ptr, csr_src);
        // fused: gates(catR @ Bcat2_l^T) -> catW[:,128:256] (new h, bf16)
        gemm_gru<<<dim3(mtiles, 4), 256, 0, stream>>>(
            catR, catW, Bcat + (size_t)l * 512 * 256, bc + (size_t)l * 512);
    }

    // after 4 layers (even), final h lives in catA[:,128:256]
    pool_sorted<<<N_GRAPHS, 256, 0, stream>>>(catA, goff, hg);
    fc12<<<N_GRAPHS, 128, 0, stream>>>(hg, fc1_w, fc1_b, fc2_w, fc2_b, lgts);
    logsoftmax_axis0<<<N_CLASSES, 512, 0, stream>>>(lgts, out);
}

// Round 13
// 405.758 us; speedup vs baseline: 1.3032x; 1.0380x over previous
//
#include <hip/hip_runtime.h>
#include <math.h>

#define N_NODES 50000
#define N_EDGES 600000
#define D 128
#define N_GRAPHS 512
#define N_CLASSES 10
#define N_LAYERS 4
#define NBLK_SCAN 196   // ceil(50000/256)
#define MTILES 391      // ceil(50000/128)
#define XG 49           // ceil(391/8)

typedef __attribute__((ext_vector_type(8))) short bf16x8;
typedef __attribute__((ext_vector_type(4))) float f32x4;

__device__ inline unsigned short f2bf(float f) {
    union { float f; unsigned int u; } v; v.f = f;
    unsigned int r = (v.u + 0x7fffu + ((v.u >> 16) & 1u)) >> 16;
    return (unsigned short)r;
}
__device__ inline float bf2f(unsigned short u) {
    union { unsigned int u; float f; } v; v.u = ((unsigned int)u) << 16;
    return v.f;
}

// async global -> LDS, 16B per lane; LDS dest = wave-uniform base + lane*16
typedef __attribute__((address_space(1))) const void GV;
typedef __attribute__((address_space(3))) void LV;
__device__ __forceinline__ void dma16(const void* g, void* l) {
    __builtin_amdgcn_global_load_lds((GV*)g, (LV*)l, 16, 0, 0);
}

// ---------------- fused init: h bf16 mirror + weights bf16 + bias + graph bounds + deg=0 ----------------
__global__ __launch_bounds__(256) void init_all(const float* __restrict__ h_in,
                                                const float* __restrict__ Ws,
                                                const float* __restrict__ Wih,
                                                const float* __restrict__ Whh,
                                                const float* __restrict__ bih,
                                                const float* __restrict__ bhh,
                                                const int* __restrict__ batch,
                                                unsigned short* __restrict__ catA,
                                                unsigned short* __restrict__ Ws_bf,
                                                unsigned short* __restrict__ Wih_bf,
                                                unsigned short* __restrict__ Whh_bf,
                                                float* __restrict__ bc,
                                                int* __restrict__ goff,
                                                int* __restrict__ deg) {
    int idx = blockIdx.x * 256 + threadIdx.x;
    if (idx < N_NODES * D) {
        int i = idx >> 7;
        int c = idx & 127;
        catA[(size_t)i * 256 + 128 + c] = f2bf(h_in[idx]);
    }
    if (idx < N_LAYERS * D * D) Ws_bf[idx] = f2bf(Ws[idx]);
    if (idx < N_LAYERS * 3 * D * D) {
        Wih_bf[idx] = f2bf(Wih[idx]);
        Whh_bf[idx] = f2bf(Whh[idx]);
    }
    if (idx < N_LAYERS * 512) {
        int l = idx >> 9;
        int j = idx & 511;
        const float* bi = bih + (size_t)l * 384;
        const float* bh = bhh + (size_t)l * 384;
        float v;
        if (j < 256) v = bi[j] + bh[j];
        else if (j < 384) v = bi[j];
        else v = bh[j - 128];
        bc[idx] = v;
    }
    if (idx < N_NODES) deg[idx] = 0;
    if (idx < N_GRAPHS) {
        int g = idx;
        int lo = 0, hi = N_NODES;
        while (lo < hi) { int mid = (lo + hi) >> 1; if (batch[mid] < g) lo = mid + 1; else hi = mid; }
        goff[g] = lo;
        if (g == 0) goff[N_GRAPHS] = N_NODES;
    }
}

// ---------------- build B_cat2[l][512][256], gate-interleaved columns ----------------
__global__ __launch_bounds__(256) void build_bcat(const unsigned short* __restrict__ Wp,
                                                  const unsigned short* __restrict__ Whh,
                                                  unsigned short* __restrict__ Bcat) {
    int idx = blockIdx.x * 256 + threadIdx.x;   // L*512*256
    if (idx >= N_LAYERS * 512 * 256) return;
    int l = idx >> 17;
    int rem = idx & 131071;
    int jp = rem >> 8;
    int k = rem & 255;
    int gate = jp & 3;
    int ch = jp >> 2;
    int j = gate * 128 + ch;
    unsigned short v = 0;
    if (j < 256) {
        v = (k < 128) ? Wp[((size_t)l * 384 + j) * 128 + k]
                      : Whh[((size_t)l * 384 + j) * 128 + (k - 128)];
    } else if (j < 384) {
        v = (k < 128) ? Wp[((size_t)l * 384 + j) * 128 + k] : (unsigned short)0;
    } else {
        v = (k >= 128) ? Whh[((size_t)l * 384 + (j - 128)) * 128 + (k - 128)] : (unsigned short)0;
    }
    Bcat[idx] = v;
}

// ---------------- CSR build ----------------
__global__ __launch_bounds__(256) void hist_dst(const int* __restrict__ dst,
                                                int* __restrict__ deg) {
    int e = blockIdx.x * 256 + threadIdx.x;
    if (e < N_EDGES) atomicAdd(&deg[dst[e]], 1);
}

__global__ __launch_bounds__(256) void block_sum(const int* __restrict__ deg,
                                                 int* __restrict__ bsum) {
    __shared__ int s[256];
    int t = threadIdx.x;
    int i = blockIdx.x * 256 + t;
    s[t] = (i < N_NODES) ? deg[i] : 0;
    __syncthreads();
    for (int o = 128; o > 0; o >>= 1) {
        if (t < o) s[t] += s[t + o];
        __syncthreads();
    }
    if (t == 0) bsum[blockIdx.x] = s[0];
}

__global__ __launch_bounds__(256) void scan_partials(const int* __restrict__ bsum,
                                                     int* __restrict__ boff,
                                                     int* __restrict__ row_ptr) {
    __shared__ int s[256];
    int t = threadIdx.x;
    int v = (t < NBLK_SCAN) ? bsum[t] : 0;
    s[t] = v;
    __syncthreads();
    for (int o = 1; o < 256; o <<= 1) {
        int x = (t >= o) ? s[t - o] : 0;
        __syncthreads();
        s[t] += x;
        __syncthreads();
    }
    if (t < NBLK_SCAN) boff[t] = s[t] - v;   // exclusive
    if (t == 255) row_ptr[N_NODES] = s[255];
}

__global__ __launch_bounds__(256) void scan_final(const int* __restrict__ deg,
                                                  const int* __restrict__ boff,
                                                  int* __restrict__ row_ptr,
                                                  int* __restrict__ pos) {
    __shared__ int s[256];
    int t = threadIdx.x;
    int i = blockIdx.x * 256 + t;
    int v = (i < N_NODES) ? deg[i] : 0;
    s[t] = v;
    __syncthreads();
    for (int o = 1; o < 256; o <<= 1) {
        int x = (t >= o) ? s[t - o] : 0;
        __syncthreads();
        s[t] += x;
        __syncthreads();
    }
    int excl = s[t] - v + boff[blockIdx.x];
    if (i < N_NODES) {
        row_ptr[i] = excl;
        pos[i] = excl;
    }
}

__global__ __launch_bounds__(256) void fill_csr(const int* __restrict__ src,
                                                const int* __restrict__ dst,
                                                int* __restrict__ pos,
                                                int* __restrict__ csr_src) {
    int e = blockIdx.x * 256 + threadIdx.x;
    if (e >= N_EDGES) return;
    int p = atomicAdd(&pos[dst[e]], 1);
    csr_src[p] = src[e];
}

// ---------------- gather: one wave per node, 4-way edge-parallel + shuffle reduce ----------------
__global__ __launch_bounds__(256) void gather_agg(unsigned short* __restrict__ cat,
                                                  const int* __restrict__ row_ptr,
                                                  const int* __restrict__ csr_src) {
    int t = threadIdx.x;
    int node = blockIdx.x * 4 + (t >> 6);
    int lane = t & 63;
    int eg = lane >> 4;          // 0..3 edge-group
    int c8 = (lane & 15) * 8;    // channel chunk
    if (node >= N_NODES) return;
    int b = row_ptr[node];
    int e2 = row_ptr[node + 1];
    float acc0[8] = {}, acc1[8] = {};
    int e = b + eg;
    for (; e + 4 < e2; e += 8) {
        int s0 = csr_src[e];
        int s1 = csr_src[e + 4];
        bf16x8 v0 = *(const bf16x8*)(cat + (size_t)s0 * 256 + 128 + c8);
        bf16x8 v1 = *(const bf16x8*)(cat + (size_t)s1 * 256 + 128 + c8);
        #pragma unroll
        for (int j = 0; j < 8; ++j) {
            acc0[j] += bf2f((unsigned short)v0[j]);
            acc1[j] += bf2f((unsigned short)v1[j]);
        }
    }
    if (e < e2) {
        int s0 = csr_src[e];
        bf16x8 v0 = *(const bf16x8*)(cat + (size_t)s0 * 256 + 128 + c8);
        #pragma unroll
        for (int j = 0; j < 8; ++j) acc0[j] += bf2f((unsigned short)v0[j]);
    }
    float a[8];
    #pragma unroll
    for (int j = 0; j < 8; ++j) a[j] = acc0[j] + acc1[j];
    #pragma unroll
    for (int j = 0; j < 8; ++j) {
        a[j] += __shfl_xor(a[j], 16, 64);
        a[j] += __shfl_xor(a[j], 32, 64);
    }
    if (eg == 0) {
        bf16x8 ov;
        #pragma unroll
        for (int j = 0; j < 8; ++j) ov[j] = (short)f2bf(a[j]);
        *(bf16x8*)(cat + (size_t)node * 256 + c8) = ov;
    }
}

// ---------------- generic bf16 MFMA GEMM (used for the tiny W' precompute) ----------------
__global__ __launch_bounds__(256) void gemm_bf16(const unsigned short* __restrict__ A, int Ap,
                                                 const unsigned short* __restrict__ W, int Wp,
                                                 unsigned short* __restrict__ out, int Op,
                                                 int M, int Kd,
                                                 size_t lsA, size_t lsW, size_t lsO) {
    A += (size_t)blockIdx.z * lsA;
    W += (size_t)blockIdx.z * lsW;
    out += (size_t)blockIdx.z * lsO;

    __shared__ unsigned short As[128 * 72];
    __shared__ unsigned short Bs[128 * 72];

    const int tid = threadIdx.x;
    const int i0 = blockIdx.x * 128;
    const int j0 = blockIdx.y * 128;

    const int wave = tid >> 6;
    const int lane = tid & 63;
    const int m16 = lane & 15;
    const int quad = lane >> 4;
    const int mr = (wave & 1) * 64;
    const int nc = (wave >> 1) * 64;

    f32x4 acc[4][4];
    #pragma unroll
    for (int a = 0; a < 4; ++a)
        #pragma unroll
        for (int b = 0; b < 4; ++b)
            acc[a][b] = (f32x4){0.f, 0.f, 0.f, 0.f};

    const int r0 = tid >> 3;
    const int kk = (tid & 7) * 8;

    for (int kc = 0; kc < Kd; kc += 64) {
        if (kc) __syncthreads();
        #pragma unroll
        for (int it = 0; it < 4; ++it) {
            int r = r0 + it * 32;
            int gi_ = i0 + r;
            bf16x8 av = {0, 0, 0, 0, 0, 0, 0, 0};
            if (gi_ < M) av = *(const bf16x8*)(A + (size_t)gi_ * Ap + kc + kk);
            *(bf16x8*)&As[r * 72 + kk] = av;
            *(bf16x8*)&Bs[r * 72 + kk] = *(const bf16x8*)(W + (size_t)(j0 + r) * Wp + kc + kk);
        }
        __syncthreads();

        #pragma unroll
        for (int ks = 0; ks < 64; ks += 32) {
            bf16x8 af[4], bf_[4];
            #pragma unroll
            for (int rt = 0; rt < 4; ++rt)
                af[rt] = *(const bf16x8*)&As[(mr + rt * 16 + m16) * 72 + ks + quad * 8];
            #pragma unroll
            for (int ct = 0; ct < 4; ++ct)
                bf_[ct] = *(const bf16x8*)&Bs[(nc + ct * 16 + m16) * 72 + ks + quad * 8];
            #pragma unroll
            for (int rt = 0; rt < 4; ++rt)
                #pragma unroll
                for (int ct = 0; ct < 4; ++ct)
                    acc[rt][ct] = __builtin_amdgcn_mfma_f32_16x16x32_bf16(
                        af[rt], bf_[ct], acc[rt][ct], 0, 0, 0);
        }
    }

    #pragma unroll
    for (int rt = 0; rt < 4; ++rt) {
        #pragma unroll
        for (int r4 = 0; r4 < 4; ++r4) {
            int i = i0 + mr + rt * 16 + quad * 4 + r4;
            if (i >= M) continue;
            #pragma unroll
            for (int ct = 0; ct < 4; ++ct) {
                int j = j0 + nc + ct * 16 + m16;
                out[(size_t)i * Op + j] = f2bf(acc[rt][ct][r4]);
            }
        }
    }
}

// ---------------- fused GEMM + GRU gates: async staging + XOR swizzle + XCD-aware mapping ----------------
// 1D grid, decode b = xcd + 8*(y + 4*xg): the 4 j'-tiles (y) sharing a node tile (x)
// get the same b%8 -> same XCD -> catR rows fetched into that XCD's L2 once.
__global__ __launch_bounds__(256) void gemm_gru(const unsigned short* __restrict__ catR,
                                                unsigned short* __restrict__ catW,
                                                const unsigned short* __restrict__ W,
                                                const float* __restrict__ bc) {
    __shared__ unsigned short As[128 * 64];   // weight tile; reused as Lo in epilogue
    __shared__ unsigned short Bs[128 * 64];   // node tile
    unsigned short* Lo = As;                  // [128][40] bf16 out staging (10240 B)

    const int bq = blockIdx.x;
    const int xcd = bq & 7;
    const int tt = bq >> 3;
    const int yb = tt & 3;               // j' tile
    const int xg = tt >> 2;              // node-tile group
    const int xb = xg * 8 + xcd;
    if (xb >= MTILES) return;

    const int tid = threadIdx.x;
    const int i0 = xb * 128;   // node base
    const int j0 = yb * 128;   // j' base
    const int ch_base = yb * 32;

    const int wave = tid >> 6;
    const int lane = tid & 63;
    const int m16 = lane & 15;
    const int quad = lane >> 4;
    const int mr = (wave & 1) * 64;    // j' sub-tile
    const int nc = (wave >> 1) * 64;   // node sub-tile
    const int chw = ch_base + (wave & 1) * 16;

    const int rb = lane >> 3;                       // 0..7
    const int cswz = (((lane & 7) ^ rb) * 8);       // ushort offset of fetched chunk

    const int h_chunk = (ch_base & 64) ? 192 : 128;

    f32x4 acc[4][4];
    #pragma unroll
    for (int a = 0; a < 4; ++a)
        #pragma unroll
        for (int b = 0; b < 4; ++b)
            acc[a][b] = (f32x4){0.f, 0.f, 0.f, 0.f};

    float hold[4][4];

    for (int kc = 0; kc < 256; kc += 64) {
        if (kc) __syncthreads();
        #pragma unroll
        for (int it = 0; it < 4; ++it) {
            int rowbase = it * 32 + wave * 8;          // wave-uniform
            int row = rowbase + rb;
            dma16(W + (size_t)(j0 + row) * 256 + kc + cswz, &As[rowbase * 64]);
            int gn = i0 + row;
            if (gn < N_NODES)
                dma16(catR + (size_t)gn * 256 + kc + cswz, &Bs[rowbase * 64]);
        }
        __syncthreads();

        if (kc == h_chunk) {
            #pragma unroll
            for (int rt = 0; rt < 4; ++rt) {
                int ch = chw + rt * 4 + quad;
                int off = 128 + ch - h_chunk;   // 0..63 ushort within chunk
                #pragma unroll
                for (int ct = 0; ct < 4; ++ct) {
                    int row = nc + ct * 16 + m16;
                    int idx = row * 64 + (((off >> 3) ^ (row & 7)) * 8) + (off & 7);
                    hold[rt][ct] = bf2f(Bs[idx]);
                }
            }
        }

        #pragma unroll
        for (int ks = 0; ks < 64; ks += 32) {
            const int cbase = (ks >> 3) + quad;   // logical 16B chunk index
            bf16x8 af[4], bf_[4];
            #pragma unroll
            for (int rt = 0; rt < 4; ++rt) {
                int row = mr + rt * 16 + m16;
                af[rt] = *(const bf16x8*)&As[row * 64 + ((cbase ^ (row & 7)) * 8)];
            }
            #pragma unroll
            for (int ct = 0; ct < 4; ++ct) {
                int row = nc + ct * 16 + m16;
                bf_[ct] = *(const bf16x8*)&Bs[row * 64 + ((cbase ^ (row & 7)) * 8)];
            }
            #pragma unroll
            for (int rt = 0; rt < 4; ++rt)
                #pragma unroll
                for (int ct = 0; ct < 4; ++ct)
                    acc[rt][ct] = __builtin_amdgcn_mfma_f32_16x16x32_bf16(
                        af[rt], bf_[ct], acc[rt][ct], 0, 0, 0);
        }
    }

    // epilogue: gates straight from accumulators -> Lo (LDS) -> coalesced stores
    __syncthreads();
    #pragma unroll
    for (int rt = 0; rt < 4; ++rt) {
        int ch = chw + rt * 4 + quad;
        float br  = bc[ch];
        float bz  = bc[128 + ch];
        float bni = bc[256 + ch];
        float bnh = bc[384 + ch];
        int chl = ch - ch_base;   // 0..31
        #pragma unroll
        for (int ct = 0; ct < 4; ++ct) {
            int rloc = nc + ct * 16 + m16;
            float r = 1.f / (1.f + __expf(-(acc[rt][ct][0] + br)));
            float z = 1.f / (1.f + __expf(-(acc[rt][ct][1] + bz)));
            float a = acc[rt][ct][2] + bni + r * (acc[rt][ct][3] + bnh);
            a = fminf(fmaxf(a, -20.f), 20.f);
            float t2 = __expf(2.f * a);
            float n = (t2 - 1.f) / (t2 + 1.f);
            float o = (1.f - z) * n + z * hold[rt][ct];
            o = o > 0.f ? o : 0.f;
            Lo[rloc * 40 + chl] = f2bf(o);
        }
    }
    __syncthreads();
    #pragma unroll
    for (int it = 0; it < 2; ++it) {
        int unit = it * 256 + tid;      // 0..511 = 128 rows x 4 segs
        int row = unit >> 2;
        int seg = (unit & 3) * 8;
        int node = i0 + row;
        if (node < N_NODES)
            *(bf16x8*)(catW + (size_t)node * 256 + 128 + ch_base + seg) =
                *(const bf16x8*)&Lo[row * 40 + seg];
    }
}

// ---------------- fused mean-pool + fc1(elu) + fc2, one block per graph ----------------
__global__ __launch_bounds__(256) void pool_fc(const unsigned short* __restrict__ cat,
                                               const int* __restrict__ goff,
                                               const float* __restrict__ w1,
                                               const float* __restrict__ b1,
                                               const float* __restrict__ w2,
                                               const float* __restrict__ b2,
                                               float* __restrict__ logits) {
    __shared__ float red[16][16][8];   // 8 KB
    __shared__ float hgs[128];
    __shared__ float zrow[128];
    int g = blockIdx.x;
    int start = goff[g];
    int end = goff[g + 1];
    int rg = threadIdx.x >> 4;    // 0..15
    int cg = threadIdx.x & 15;    // 0..15
    float acc[8] = {};
    for (int i = start + rg; i < end; i += 16) {
        bf16x8 v = *(const bf16x8*)(cat + (size_t)i * 256 + 128 + cg * 8);
        #pragma unroll
        for (int j = 0; j < 8; ++j) acc[j] += bf2f((unsigned short)v[j]);
    }
    #pragma unroll
    for (int j = 0; j < 8; ++j) red[rg][cg][j] = acc[j];
    __syncthreads();
    for (int o = 8; o > 0; o >>= 1) {
        if (rg < o) {
            #pragma unroll
            for (int j = 0; j < 8; ++j) red[rg][cg][j] += red[rg + o][cg][j];
        }
        __syncthreads();
    }
    if (rg == 0) {
        float cnt = fmaxf((float)(end - start), 1.f);
        #pragma unroll
        for (int j = 0; j < 8; ++j) hgs[cg * 8 + j] = red[0][cg][j] / cnt;
    }
    __syncthreads();
    int t = threadIdx.x;
    if (t < 128) {
        float a1 = b1[t];
        const float* wr = w1 + (size_t)t * 128;
        #pragma unroll 4
        for (int k = 0; k < 128; ++k) a1 += hgs[k] * wr[k];
        zrow[t] = a1 > 0.f ? a1 : (expf(a1) - 1.f);
    }
    __syncthreads();
    if (t < N_CLASSES) {
        float a2 = b2[t];
        const float* w2r = w2 + (size_t)t * 128;
        #pragma unroll 4
        for (int k = 0; k < 128; ++k) a2 += zrow[k] * w2r[k];
        logits[(size_t)g * N_CLASSES + t] = a2;
    }
}

// ---------------- log_softmax over axis 0 ----------------
__global__ __launch_bounds__(512) void logsoftmax_axis0(const float* __restrict__ logits,
                                                        float* __restrict__ out) {
    __shared__ float red[512];
    int c = blockIdx.x;
    int g = threadIdx.x;
    float x = logits[(size_t)g * N_CLASSES + c];
    red[g] = x;
    __syncthreads();
    for (int s = 256; s > 0; s >>= 1) {
        if (g < s) red[g] = fmaxf(red[g], red[g + s]);
        __syncthreads();
    }
    float mx = red[0];
    __syncthreads();
    red[g] = expf(x - mx);
    __syncthreads();
    for (int s = 256; s > 0; s >>= 1) {
        if (g < s) red[g] += red[g + s];
        __syncthreads();
    }
    float lse = mx + logf(red[0]);
    out[(size_t)g * N_CLASSES + c] = x - lse;
}

// ---------------- launch ----------------
extern "C" void kernel_launch(void* const* d_in, const int* in_sizes, int n_in,
                              void* d_out, int out_size, void* d_ws, size_t ws_size,
                              hipStream_t stream) {
    const float* h_in   = (const float*)d_in[0];
    const int*   eidx   = (const int*)d_in[1];
    const int*   batch  = (const int*)d_in[3];
    const float* Ws     = (const float*)d_in[4];
    const float* W_ih   = (const float*)d_in[5];
    const float* W_hh   = (const float*)d_in[6];
    const float* b_ih   = (const float*)d_in[7];
    const float* b_hh   = (const float*)d_in[8];
    const float* fc1_w  = (const float*)d_in[9];
    const float* fc1_b  = (const float*)d_in[10];
    const float* fc2_w  = (const float*)d_in[11];
    const float* fc2_b  = (const float*)d_in[12];
    float* out = (float*)d_out;

    char* ws = (char*)d_ws;
    size_t off = 0;
    auto alloc = [&](size_t bytes) {
        void* p = ws + off;
        off += (bytes + 255) & ~(size_t)255;
        return p;
    };
    unsigned short* catA = (unsigned short*)alloc((size_t)N_NODES * 256 * 2);  // [agg | h] bf16
    unsigned short* catB = (unsigned short*)alloc((size_t)N_NODES * 256 * 2);
    unsigned short* Ws_bf  = (unsigned short*)alloc((size_t)N_LAYERS * D * D * 2);
    unsigned short* Wih_bf = (unsigned short*)alloc((size_t)N_LAYERS * 3 * D * D * 2);
    unsigned short* Whh_bf = (unsigned short*)alloc((size_t)N_LAYERS * 3 * D * D * 2);
    unsigned short* Wp_bf  = (unsigned short*)alloc((size_t)N_LAYERS * 3 * D * D * 2);  // Wih @ Ws^T
    unsigned short* Bcat   = (unsigned short*)alloc((size_t)N_LAYERS * 512 * 256 * 2);
    float* bc   = (float*)alloc((size_t)N_LAYERS * 512 * 4);
    float* lgts = (float*)alloc((size_t)N_GRAPHS * N_CLASSES * 4);
    int* deg     = (int*)alloc((size_t)N_NODES * 4);
    int* row_ptr = (int*)alloc((size_t)(N_NODES + 1) * 4);
    int* pos     = (int*)alloc((size_t)N_NODES * 4);
    int* csr_src = (int*)alloc((size_t)N_EDGES * 4);
    int* bsum    = (int*)alloc((size_t)NBLK_SCAN * 4);
    int* boff    = (int*)alloc((size_t)NBLK_SCAN * 4);
    int* goff    = (int*)alloc((size_t)(N_GRAPHS + 1) * 4);

    const int* src = eidx;
    const int* dst = eidx + N_EDGES;

    init_all<<<(N_NODES * D + 255) / 256, 256, 0, stream>>>(
        h_in, Ws, W_ih, W_hh, b_ih, b_hh, batch,
        catA, Ws_bf, Wih_bf, Whh_bf, bc, goff, deg);

    // W'_l = Wih_l @ Ws_l^T, batched over layers via grid.z
    gemm_bf16<<<dim3(3, 1, N_LAYERS), 256, 0, stream>>>(
        Wih_bf, 128, Ws_bf, 128, Wp_bf, 128, 384, 128,
        (size_t)384 * 128, (size_t)128 * 128, (size_t)384 * 128);
    build_bcat<<<(N_LAYERS * 512 * 256 + 255) / 256, 256, 0, stream>>>(Wp_bf, Whh_bf, Bcat);

    // CSR build (edges static) — distributed scan
    hist_dst<<<(N_EDGES + 255) / 256, 256, 0, stream>>>(dst, deg);
    block_sum<<<NBLK_SCAN, 256, 0, stream>>>(deg, bsum);
    scan_partials<<<1, 256, 0, stream>>>(bsum, boff, row_ptr);
    scan_final<<<NBLK_SCAN, 256, 0, stream>>>(deg, boff, row_ptr, pos);
    fill_csr<<<(N_EDGES + 255) / 256, 256, 0, stream>>>(src, dst, pos, csr_src);

    const int ggrid = XG * 4 * 8;   // 1568 (XCD-aware decode inside)
    for (int l = 0; l < N_LAYERS; ++l) {
        unsigned short* catR = (l & 1) ? catB : catA;
        unsigned short* catW = (l & 1) ? catA : catB;
        // catR[:,0:128] = gather of catR[:,128:256]  (agg of h)
        gather_agg<<<(N_NODES + 3) / 4, 256, 0, stream>>>(catR, row_ptr, csr_src);
        // fused: gates(catR @ Bcat2_l^T) -> catW[:,128:256] (new h, bf16)
        gemm_gru<<<ggrid, 256, 0, stream>>>(
            catR, catW, Bcat + (size_t)l * 512 * 256, bc + (size_t)l * 512);
    }

    // after 4 layers (even), final h lives in catA[:,128:256]
    pool_fc<<<N_GRAPHS, 256, 0, stream>>>(catA, goff, fc1_w, fc1_b, fc2_w, fc2_b, lgts);
    logsoftmax_axis0<<<N_CLASSES, 512, 0, stream>>>(lgts, out);
}